// Round 7
// baseline (1732.034 us; speedup 1.0000x reference)
//
#include <hip/hip_runtime.h>
#include <math.h>

#define CDIV(a,b) (((a)+(b)-1)/(b))

typedef __attribute__((ext_vector_type(8))) short short8v;   // 8 bf16 = 4 VGPRs
typedef __attribute__((ext_vector_type(4))) float float4v;

__device__ __forceinline__ ushort f2b(float f) {
  union { float f; unsigned u; } v; v.f = f;
  unsigned r = (v.u + 0x7fffu + ((v.u >> 16) & 1u)) >> 16;   // RNE
  return (ushort)r;
}
__device__ __forceinline__ float b2f(ushort h) {
  union { unsigned u; float f; } v; v.u = ((unsigned)h) << 16;
  return v.f;
}

// async global->LDS, 16B per lane; lds base must be wave-uniform (HW adds lane*16)
__device__ __forceinline__ void gload_lds16(const ushort* g, ushort* l) {
  __builtin_amdgcn_global_load_lds(
      (const __attribute__((address_space(1))) void*)g,
      (__attribute__((address_space(3))) void*)l, 16, 0, 0);
}

// ---------------------------------------------------------------- elementwise (vectorized)
__global__ __launch_bounds__(256) void copy4_kernel(float4* __restrict__ dst,
                                                    const float4* __restrict__ src, int n4) {
  int i = blockIdx.x*256 + threadIdx.x;
  if (i < n4) dst[i] = src[i];
}

__global__ __launch_bounds__(256) void add4_kernel(float4* __restrict__ x,
                                                   const float4* __restrict__ y, int n4) {
  int i = blockIdx.x*256 + threadIdx.x;
  if (i >= n4) return;
  float4 a = x[i], b = y[i];
  a.x += b.x; a.y += b.y; a.z += b.z; a.w += b.w;
  x[i] = a;
}

// ---------------------------------------------------------------- LayerNorm, one wave per row
__global__ __launch_bounds__(256) void ln_kernel(const float* __restrict__ in,
    const float* __restrict__ g, const float* __restrict__ b,
    float* __restrict__ outf, ushort* __restrict__ outb, int C, float eps, int nrows)
{
  int row = blockIdx.x*4 + (threadIdx.x >> 6);
  int lane = threadIdx.x & 63;
  if (row >= nrows) return;
  const float* rp = in + (size_t)row*C;
  float s = 0.f, s2 = 0.f;
  for (int c = lane; c < C; c += 64) { float v = rp[c]; s += v; s2 += v*v; }
  #pragma unroll
  for (int off = 32; off > 0; off >>= 1) { s += __shfl_xor(s, off); s2 += __shfl_xor(s2, off); }
  float mean = s / C;
  float var  = s2 / C - mean*mean;
  float inv  = rsqrtf(var + eps);
  for (int c = lane; c < C; c += 64) {
    float v = (rp[c]-mean)*inv*g[c] + b[c];
    if (outb) outb[(size_t)row*C + c] = f2b(v);
    else      outf[(size_t)row*C + c] = v;
  }
}

// ---------------------------------------------------------------- window partition (bf16, 8-wide)
__global__ __launch_bounds__(256) void winpart_kernel(const ushort* __restrict__ in,
                                                      ushort* __restrict__ out) {
  int i = blockIdx.x*256 + threadIdx.x;          // over 25*196*96 uint4 units
  if (i >= 25*196*96) return;
  int c8 = i % 96; int t = (i / 96) % 196; int b = i / (96*196);
  int wy = b / 5, wx = b % 5;
  int iy = t / 14, ix = t % 14;
  int h = wy*14 + iy, w = wx*14 + ix;
  uint4 v = {0u,0u,0u,0u};
  if (h < 64 && w < 64) v = *(const uint4*)(in + ((size_t)(h*64 + w))*768 + c8*8);
  *(uint4*)(out + (size_t)i*8) = v;
}

// window unpartition + residual add (float4)
__global__ __launch_bounds__(256) void unpart_add_kernel(float* __restrict__ x,
                                                         const float* __restrict__ p) {
  int i = blockIdx.x*256 + threadIdx.x;          // over 4096*192 float4 units
  if (i >= 4096*192) return;
  int c4 = i % 192; int hw = i / 192; int w = hw % 64; int h = hw / 64;
  int wy = h/14, iy = h%14, wx = w/14, ix = w%14;
  int b = wy*5 + wx; int t = iy*14 + ix;
  float4 a = *(const float4*)(x + (size_t)i*4);
  float4 r = *(const float4*)(p + ((size_t)(b*196 + t))*768 + c4*4);
  a.x += r.x; a.y += r.y; a.z += r.z; a.w += r.w;
  *(float4*)(x + (size_t)i*4) = a;
}

// ---------------------------------------------------------------- weight transpose+convert: in [K][N] f32 -> out [N][K] bf16
__global__ __launch_bounds__(256) void transpose_cvt_kernel(const float* __restrict__ in,
    ushort* __restrict__ out, int K, int N)
{
  __shared__ float t[32][33];
  int n0 = blockIdx.x*32, k0 = blockIdx.y*32;
  int cc = threadIdx.x & 31, rr = threadIdx.x >> 5;
  for (int r = rr; r < 32; r += 8) t[r][cc] = in[(size_t)(k0+r)*N + n0 + cc];
  __syncthreads();
  for (int r = rr; r < 32; r += 8) out[(size_t)(n0+r)*K + k0 + cc] = f2b(t[cc][r]);
}

// f32 transpose: in [R][Cc] -> out [Cc][R]  (for NHWC->NCHW)
__global__ __launch_bounds__(256) void transpose_f32_kernel(const float* __restrict__ in,
    float* __restrict__ out, int R, int Cc)
{
  __shared__ float t[32][33];
  int c0 = blockIdx.x*32, r0 = blockIdx.y*32;
  int cc = threadIdx.x & 31, rr = threadIdx.x >> 5;
  for (int r = rr; r < 32; r += 8) t[r][cc] = in[(size_t)(r0+r)*Cc + c0 + cc];
  __syncthreads();
  for (int r = rr; r < 32; r += 8) out[(size_t)(c0+r)*R + r0 + cc] = t[cc][r];
}

// ---------------------------------------------------------------- V transpose: qkv v-slice -> vt[wn][64 dim][strideV keys] bf16
// perm!=0: within each 64-key tile, physical column p holds key (p&3)*16 + (p>>2)
// (matches attn4's packed-b64 P layout; PV sum is permutation-invariant)
__global__ __launch_bounds__(256) void vtrans_kernel(const ushort* __restrict__ qkv,
    ushort* __restrict__ vt, int T, int strideV, int perm)
{
  __shared__ ushort tile[64*72];
  int kt = blockIdx.x, wn = blockIdx.y;
  int win = wn / 12, n = wn - win*12;
  int tid = threadIdx.x;
  size_t tokBase = (size_t)win * T;
  int k0 = kt*64;
  #pragma unroll
  for (int it=0; it<2; ++it) {
    int id = tid + it*256;
    int r = id >> 3, ch = id & 7;
    int kk = k0 + r; if (kk >= T) kk = T-1;
    *(uint4*)(tile + r*72 + ch*8) =
      *(const uint4*)(qkv + (tokBase + kk)*2304 + 1536 + n*64 + ch*8);
  }
  __syncthreads();
  #pragma unroll
  for (int it=0; it<2; ++it) {
    int id = tid + it*256;
    int d = id & 63, kg = id >> 6;     // kg 0..7
    union { uint4 v; ushort u[8]; } o;
    #pragma unroll
    for (int j=0;j<8;++j) {
      int p = kg*8 + j;
      int kl = perm ? ((p & 3)*16 + (p >> 2)) : p;
      o.u[j] = tile[kl*72 + d];
    }
    *(uint4*)(vt + ((size_t)wn*64 + d)*strideV + k0 + kg*8) = o.v;
  }
}

// ---------------------------------------------------------------- bf16 MFMA GEMM
// m97 structure + bijective XCD swizzle (m204), templated tile:
//   <128,128>: 2x2 waves, 64x64/wave (original)
//   <64,128>:  1x4 waves, 64x32/wave  (narrow-N: proj, fc2 — doubles grid)
//   <64,64>:   1x4 waves, 64x16/wave  (neck convs — 4x grid)
// Staging: (BM+BN)/16 16-row DMA slots round-robin over 4 waves (all configs divide).
template<int BM, int BN>
__global__ __launch_bounds__(256) void gemm_bf16_kernel(
    const ushort* __restrict__ A, const ushort* __restrict__ Bt,
    const float* __restrict__ bias, const float* __restrict__ res,
    float* __restrict__ Cf, ushort* __restrict__ Cb,
    int M, int N, int K, int act)
{
  constexpr int WMW = (BM == 128) ? 2 : 1;   // waves along M
  constexpr int WNW = 4 / WMW;               // waves along N
  constexpr int MI  = BM / (WMW*16);
  constexpr int NI  = BN / (WNW*16);
  constexpr int ASLOTS = BM/16;
  constexpr int TSLOTS = (BM+BN)/16;
  constexpr int NSLOT  = TSLOTS/4;           // per-wave DMA slots

  __shared__ ushort Al[BM*32];
  __shared__ ushort Bl[BN*32];
  int tid = threadIdx.x;
  int lane = tid & 63, wave = tid >> 6;
  int wm = (WMW==2) ? (wave & 1) : 0;
  int wn = (WMW==2) ? (wave >> 1) : wave;
  int l15 = lane & 15, lq = lane >> 4;

  // bijective XCD-aware remap (m204)
  int gx = gridDim.x;
  int nwg = gx * gridDim.y;
  int orig = blockIdx.y * gx + blockIdx.x;
  int q8 = nwg >> 3, r8 = nwg & 7;
  int xcd = orig & 7, within = orig >> 3;
  int lin = (xcd < r8 ? xcd*(q8+1) : r8*(q8+1) + (xcd-r8)*q8) + within;
  int bx = lin % gx, by = lin / gx;

  int rowBase = by * BM, colBase = bx * BN;
  float4v acc[MI][NI];
  #pragma unroll
  for (int i=0;i<MI;++i)
    #pragma unroll
    for (int j=0;j<NI;++j) acc[i][j] = (float4v){0.f,0.f,0.f,0.f};

  int cs  = (lane&3) ^ ((lane>>3)&3);   // staged source chunk (XOR key = (row>>1)&3)
  int rsl = lane >> 2;                  // row within 16-row slot

  const ushort* gsrc[NSLOT];
  ushort* ldst[NSLOT];
  #pragma unroll
  for (int s=0; s<NSLOT; ++s) {
    int ls = wave + 4*s;
    if (ls < ASLOTS) {
      int gr = rowBase + ls*16 + rsl; if (gr >= M) gr = M-1;
      gsrc[s] = A + (size_t)gr*K + cs*8;
      ldst[s] = Al + (ls*16)*32;
    } else {
      int lb = ls - ASLOTS;
      int gc = colBase + lb*16 + rsl;          // N % BN == 0 at all call sites
      gsrc[s] = Bt + (size_t)gc*K + cs*8;
      ldst[s] = Bl + (lb*16)*32;
    }
  }

  int sA = (l15 >> 1) & 3;
  int rdOff = ((lq ^ sA) << 3);

  for (int k0 = 0; k0 < K; k0 += 32) {
    __syncthreads();
    #pragma unroll
    for (int s=0; s<NSLOT; ++s) gload_lds16(gsrc[s] + k0, ldst[s]);
    __syncthreads();
    short8v af[MI], bf[NI];
    #pragma unroll
    for (int mi=0; mi<MI; ++mi)
      af[mi] = *(const short8v*)(Al + (wm*(BM/WMW) + mi*16 + l15)*32 + rdOff);
    #pragma unroll
    for (int ni=0; ni<NI; ++ni)
      bf[ni] = *(const short8v*)(Bl + (wn*(BN/WNW) + ni*16 + l15)*32 + rdOff);
    #pragma unroll
    for (int mi=0; mi<MI; ++mi)
      #pragma unroll
      for (int ni=0; ni<NI; ++ni)
        acc[mi][ni] = __builtin_amdgcn_mfma_f32_16x16x32_bf16(af[mi], bf[ni], acc[mi][ni], 0, 0, 0);
  }
  #pragma unroll
  for (int mi=0; mi<MI; ++mi) {
    int gr0e = rowBase + wm*(BM/WMW) + mi*16 + lq*4;
    #pragma unroll
    for (int ni=0; ni<NI; ++ni) {
      int gc = colBase + wn*(BN/WNW) + ni*16 + l15;
      float bsv = bias ? bias[gc] : 0.f;
      #pragma unroll
      for (int r=0; r<4; ++r) {
        int gr = gr0e + r;
        if (gr < M) {
          float v = acc[mi][ni][r] + bsv;
          if (act) v = 0.5f*v*(1.f + erff(v*0.70710678118f));
          if (res) v += res[(size_t)gr*N + gc];
          if (Cf) Cf[(size_t)gr*N + gc] = v;
          if (Cb) Cb[(size_t)gr*N + gc] = f2b(v);
        }
      }
    }
  }
}

// ---------------------------------------------------------------- im2col for 3x3 SAME conv, bf16, 64x64x256
__global__ __launch_bounds__(256) void im2col3_kernel(const ushort* __restrict__ in,
                                                      ushort* __restrict__ out)
{
  int gid = blockIdx.x*256 + threadIdx.x;      // over 4096*288 uint4 units
  if (gid >= 4096*288) return;
  int u = gid % 288;  int p = gid / 288;
  int x = p & 63, y = p >> 6;
  int tap = u >> 5;
  int cu  = u & 31;
  int dy = tap / 3, dx = tap - dy*3;
  int yy = y + dy - 1, xx = x + dx - 1;
  uint4 v = {0u,0u,0u,0u};
  if (yy >= 0 && yy < 64 && xx >= 0 && xx < 64)
    v = *(const uint4*)(in + ((size_t)(yy*64 + xx))*256 + cu*8);
  *(uint4*)(out + (size_t)p*2304 + u*8) = v;
}

// ---------------------------------------------------------------- decomposed rel-pos bias (bf16 qkv in, bf16 out)
__global__ __launch_bounds__(256) void relbias_kernel(const ushort* __restrict__ qkv,
    const float* __restrict__ table, ushort* __restrict__ out,
    int nWin, int T, int S, int useH)
{
  int gid = blockIdx.x*256 + threadIdx.x;
  int total = nWin*12*T*S;
  if (gid >= total) return;
  int kk = gid % S; int r = gid / S;
  int t = r % T; int r2 = r / T; int n = r2 % 12; int b = r2 / 12;
  int coord = useH ? (t / S) : (t % S);
  const ushort* q = qkv + ((size_t)(b*T + t))*2304 + n*64;
  const float* tb = table + (size_t)(coord - kk + S - 1)*64;
  float s0=0.f, s1=0.f;
  #pragma unroll
  for (int d=0; d<64; d+=2) { s0 = fmaf(b2f(q[d]), tb[d], s0); s1 = fmaf(b2f(q[d+1]), tb[d+1], s1); }
  out[gid] = f2b(s0 + s1);
}

// ---------------------------------------------------------------- MFMA flash attention (windowed)
// Fixed-max softmax (M0=8 folded into RWl), deferred l-reduce, pre-transposed V.
template<int S>
__global__ __launch_bounds__(256) void attn3_kernel(
    const ushort* __restrict__ qkv, const ushort* __restrict__ rh,
    const ushort* __restrict__ rw, const ushort* __restrict__ vtw,
    ushort* __restrict__ outb, int T)
{
  constexpr int SP = (S + 15) & ~15;
  __shared__ ushort Ql[64*72];
  __shared__ ushort Kl[64*72];
  __shared__ ushort Vt[64*72];
  __shared__ ushort Pl[64*72];
  __shared__ ushort RHl[64*SP];
  __shared__ ushort RWl[64*SP];

  int qt = blockIdx.x, n = blockIdx.y, b = blockIdx.z;
  int wn = b*12 + n;
  int tid = threadIdx.x, lane = tid & 63, w = tid >> 6;
  int l15 = lane & 15, lq = lane >> 4;
  size_t tokBase = (size_t)b * T;
  int q0 = qt * 64;

  #pragma unroll
  for (int it = 0; it < 2; ++it) {
    int id = tid + it*256;
    int r = id >> 3, ch = id & 7;
    int qq = q0 + r; if (qq >= T) qq = T - 1;
    *(uint4*)(Ql + r*72 + ch*8) =
        *(const uint4*)(qkv + (tokBase + qq)*2304 + n*64 + ch*8);
  }
  for (int idx = tid; idx < 64*S; idx += 256) {
    int r = idx / S, c = idx - r*S;
    int qq = q0 + r; if (qq >= T) qq = T - 1;
    size_t base = ((size_t)(b*12 + n)*T + qq)*S;
    RHl[r*SP + c] = rh[base + c];
    RWl[r*SP + c] = f2b(b2f(rw[base + c]) - 8.0f);   // fold fixed max
  }
  __syncthreads();
  short8v aq0 = *(const short8v*)(Ql + (w*16 + l15)*72 + lq*8);
  short8v aq1 = *(const short8v*)(Ql + (w*16 + l15)*72 + 32 + lq*8);

  float lacc[4] = {0.f,0.f,0.f,0.f};
  float4v O[4];
  #pragma unroll
  for (int i=0;i<4;++i) O[i] = (float4v){0.f,0.f,0.f,0.f};

  int nkt = (T + 63) >> 6;
  for (int kt = 0; kt < nkt; ++kt) {
    int k0 = kt*64;
    __syncthreads();
    #pragma unroll
    for (int it=0; it<2; ++it) {
      int id = tid + it*256;
      int r = id >> 3, ch = id & 7;
      int kk = k0 + r; if (kk >= T) kk = T-1;
      *(uint4*)(Kl + r*72 + ch*8) =
        *(const uint4*)(qkv + (tokBase + kk)*2304 + 768 + n*64 + ch*8);
      *(uint4*)(Vt + r*72 + ch*8) =
        *(const uint4*)(vtw + ((size_t)wn*64 + r)*256 + k0 + ch*8);
    }
    __syncthreads();

    float4v Sv[4];
    #pragma unroll
    for (int ni=0; ni<4; ++ni) {
      short8v bk0 = *(const short8v*)(Kl + (ni*16 + l15)*72 + lq*8);
      short8v bk1 = *(const short8v*)(Kl + (ni*16 + l15)*72 + 32 + lq*8);
      float4v s = (float4v){0.f,0.f,0.f,0.f};
      s = __builtin_amdgcn_mfma_f32_16x16x32_bf16(aq0, bk0, s, 0,0,0);
      s = __builtin_amdgcn_mfma_f32_16x16x32_bf16(aq1, bk1, s, 0,0,0);
      Sv[ni] = s;
    }

    #pragma unroll
    for (int r=0;r<4;++r) {
      int qlrow = w*16 + lq*4 + r;
      #pragma unroll
      for (int ni=0;ni<4;++ni) {
        int key = k0 + ni*16 + l15;
        int kcl = key < T ? key : 0;
        int kh = kcl / S, kw = kcl - kh*S;
        float sc = key < T
          ? fmaf(Sv[ni][r], 0.125f, b2f(RHl[qlrow*SP+kh]) + b2f(RWl[qlrow*SP+kw]))
          : -1e30f;
        float pv = __expf(sc);
        lacc[r] += pv;
        union { float f; unsigned u; } cv; cv.f = pv;
        Pl[qlrow*72 + ni*16 + l15] = (ushort)((cv.u + 0x8000u) >> 16);
      }
    }

    short8v ap0 = *(const short8v*)(Pl + (w*16 + l15)*72 + lq*8);
    short8v ap1 = *(const short8v*)(Pl + (w*16 + l15)*72 + 32 + lq*8);
    #pragma unroll
    for (int ni=0;ni<4;++ni) {
      short8v bv0 = *(const short8v*)(Vt + (ni*16 + l15)*72 + lq*8);
      short8v bv1 = *(const short8v*)(Vt + (ni*16 + l15)*72 + 32 + lq*8);
      O[ni] = __builtin_amdgcn_mfma_f32_16x16x32_bf16(ap0, bv0, O[ni], 0,0,0);
      O[ni] = __builtin_amdgcn_mfma_f32_16x16x32_bf16(ap1, bv1, O[ni], 0,0,0);
    }
  }

  #pragma unroll
  for (int r=0;r<4;++r) {
    int qlrow = w*16 + lq*4 + r;
    int qg = q0 + qlrow;
    float ls = lacc[r];
    #pragma unroll
    for (int off=1; off<16; off<<=1) ls += __shfl_xor(ls, off);
    if (qg < T) {
      float inv = 1.f / ls;
      #pragma unroll
      for (int ni=0;ni<4;++ni)
        outb[(tokBase + qg)*768 + n*64 + ni*16 + l15] = f2b(O[ni][r]*inv);
    }
  }
}

// ---------------------------------------------------------------- specialized global flash attention (T=4096, S=64)
// v8 = v6 structure (best: 118us) + softmax VALU trim:
//   - P-packing via 2x v_cvt_pk_bf16_f32 (RNE, identical rounding to f2b)
//     replacing ~74 VALU ops of manual-RNE + pack per lane/tile.
//   - exp2 form: log2e prescaled into rwp (init) and rhs (4 muls/tile)
//     instead of __expf's 16 per-exp muls.
__global__ __launch_bounds__(256) void attn4_kernel(
    const ushort* __restrict__ qkv, const ushort* __restrict__ rh,
    const ushort* __restrict__ rw, const ushort* __restrict__ vtg,
    ushort* __restrict__ outb)
{
  const int T = 4096;
  __shared__ ushort Kl[2][64*64];     // linear rows (128B); phys chunk c holds logical chunk c^(row&7)
  __shared__ ushort Vl[2][64*64];
  __shared__ ushort Pl[64*64];        // wave-private rows, same chunk swizzle
  __shared__ ushort RHl[64*72];       // stride 72 (144B, 16B-aligned rows)

  int qt = blockIdx.x, n = blockIdx.y;
  int tid = threadIdx.x, lane = tid & 63, w = tid >> 6;
  int l15 = lane & 15, lq = lane >> 4;
  int q0 = qt * 64;
  const float LOG2E = 1.44269504f;

  // RH rows, wave-private mapping: wave w stages exactly rows w*16..w*16+15
  #pragma unroll
  for (int it = 0; it < 2; ++it) {
    int id2 = lane + it*64;
    int r = w*16 + (id2 >> 3), ch = id2 & 7;
    *(uint4*)(RHl + r*72 + ch*8) =
        *(const uint4*)(rh + ((size_t)n*T + q0 + r)*64 + ch*8);
  }
  // Q fragments straight from global (one-shot, no LDS round-trip)
  const ushort* qp = qkv + (size_t)(q0 + w*16 + l15)*2304 + n*64 + lq*8;
  short8v aq0 = *(const short8v*)(qp);
  short8v aq1 = *(const short8v*)(qp + 32);

  // preload this lane's rw values (kw fixed across tiles), fold fixed max -8, prescale log2e
  float rwp[4][4];
  #pragma unroll
  for (int r=0;r<4;++r)
    #pragma unroll
    for (int ni=0;ni<4;++ni)
      rwp[r][ni] = (b2f(rw[((size_t)n*T + q0 + w*16 + lq*4 + r)*64 + ni*16 + l15]) - 8.0f) * LOG2E;

  const ushort* kbase = qkv + 768 + n*64;          // + row*2304
  const ushort* vbase = vtg + (size_t)n*64*4096;   // [dim][keypos] (columns tile-permuted)
  int sr  = (lane >> 3) & 7;                       // staged row-within-8
  int sch = lane & 7;                              // staged (physical) chunk = lane&7
  int swz = ((sch ^ sr) << 3);                     // inverse-swizzled logical source chunk (ushorts)

  // per wave: 4 DMA loads/tile (2 K + 2 V), rows w*16..w*16+15, LDS dest linear
  auto stage = [&](int buf, int k0s) {
    #pragma unroll
    for (int it=0; it<2; ++it) {
      int rr = w*16 + it*8 + sr;
      gload_lds16(kbase + (size_t)(k0s + rr)*2304 + swz, &Kl[buf][(w*2+it)*512]);
      gload_lds16(vbase + (size_t)rr*4096 + k0s + swz, &Vl[buf][(w*2+it)*512]);
    }
  };

  float lacc[4] = {0.f,0.f,0.f,0.f};
  float4v O[4];
  #pragma unroll
  for (int i=0;i<4;++i) O[i] = (float4v){0.f,0.f,0.f,0.f};

  stage(0, 0);

  int xk  = (lq ^ (l15 & 7)) << 3;          // chunk lq   swizzled read offset (ushorts)
  int xk4 = ((lq ^ 4) ^ (l15 & 7)) << 3;    // chunk lq+4 swizzled

  for (int kt = 0; kt < 64; ++kt) {
    int cur = kt & 1;
    __syncthreads();
    if (kt < 63) stage(cur ^ 1, (kt+1)*64);

    const ushort* Kc = Kl[cur];
    const ushort* Vc = Vl[cur];

    float4v Sv[4];
    #pragma unroll
    for (int ni=0; ni<4; ++ni) {
      short8v bk0 = *(const short8v*)(Kc + (ni*16 + l15)*64 + xk);
      short8v bk1 = *(const short8v*)(Kc + (ni*16 + l15)*64 + xk4);
      float4v s = (float4v){0.f,0.f,0.f,0.f};
      s = __builtin_amdgcn_mfma_f32_16x16x32_bf16(aq0, bk0, s, 0,0,0);
      s = __builtin_amdgcn_mfma_f32_16x16x32_bf16(aq1, bk1, s, 0,0,0);
      Sv[ni] = s;
    }

    // softmax (fixed max, deferred l) + packed P write via v_cvt_pk_bf16_f32:
    // physical key position p = l15*4 + ni; V columns hold key (p&3)*16+(p>>2) = ni*16+l15
    #pragma unroll
    for (int r=0;r<4;++r) {
      int qlrow = w*16 + lq*4 + r;
      float rhs = b2f(RHl[qlrow*72 + kt]) * LOG2E;   // broadcast per lq-group
      float pvv[4];
      #pragma unroll
      for (int ni=0;ni<4;++ni) {
        float pv = exp2f(fmaf(Sv[ni][r], 0.18033688f, rhs + rwp[r][ni]));  // 0.125*log2e
        lacc[r] += pv;
        pvv[ni] = pv;
      }
      unsigned plo, phi;
      asm("v_cvt_pk_bf16_f32 %0, %1, %2" : "=v"(plo) : "v"(pvv[0]), "v"(pvv[1]));
      asm("v_cvt_pk_bf16_f32 %0, %1, %2" : "=v"(phi) : "v"(pvv[2]), "v"(pvv[3]));
      unsigned long long pk = ((unsigned long long)phi << 32) | (unsigned long long)plo;
      *(unsigned long long*)(Pl + qlrow*64 +
          ((((l15 >> 1)) ^ (qlrow & 7)) << 3) + (l15 & 1)*4) = pk;
    }

    // P rows are wave-private -> no barrier needed between write and read
    short8v ap0 = *(const short8v*)(Pl + (w*16 + l15)*64 + xk);
    short8v ap1 = *(const short8v*)(Pl + (w*16 + l15)*64 + xk4);
    #pragma unroll
    for (int ni=0;ni<4;++ni) {
      short8v bv0 = *(const short8v*)(Vc + (ni*16 + l15)*64 + xk);
      short8v bv1 = *(const short8v*)(Vc + (ni*16 + l15)*64 + xk4);
      O[ni] = __builtin_amdgcn_mfma_f32_16x16x32_bf16(ap0, bv0, O[ni], 0,0,0);
      O[ni] = __builtin_amdgcn_mfma_f32_16x16x32_bf16(ap1, bv1, O[ni], 0,0,0);
    }
  }

  #pragma unroll
  for (int r=0;r<4;++r) {
    int qg = q0 + w*16 + lq*4 + r;
    float ls = lacc[r];
    #pragma unroll
    for (int off=1; off<16; off<<=1) ls += __shfl_xor(ls, off);
    float inv = 1.f / ls;
    #pragma unroll
    for (int ni=0;ni<4;++ni)
      outb[(size_t)qg*768 + n*64 + ni*16 + l15] = f2b(O[ni][r]*inv);
  }
}

// ================================================================ launch
extern "C" void kernel_launch(void* const* d_in, const int* in_sizes, int n_in,
                              void* d_out, int out_size, void* d_ws, size_t ws_size,
                              hipStream_t stream)
{
  const float* x_in   = (const float*)d_in[0];
  const float* ln1_g  = (const float*)d_in[1];
  const float* ln1_b  = (const float*)d_in[2];
  const float* qkv_w  = (const float*)d_in[3];
  const float* qkv_b  = (const float*)d_in[4];
  const float* proj_w = (const float*)d_in[5];
  const float* proj_b = (const float*)d_in[6];
  const float* rel_h  = (const float*)d_in[7];
  const float* rel_w  = (const float*)d_in[8];
  const float* ln2_g  = (const float*)d_in[9];
  const float* ln2_b  = (const float*)d_in[10];
  const float* fc1_w  = (const float*)d_in[11];
  const float* fc1_b  = (const float*)d_in[12];
  const float* fc2_w  = (const float*)d_in[13];
  const float* fc2_b  = (const float*)d_in[14];
  const float* nconv1 = (const float*)d_in[15];
  const float* nln1_g = (const float*)d_in[16];
  const float* nln1_b = (const float*)d_in[17];
  const float* nconv2 = (const float*)d_in[18];
  const float* nln2_g = (const float*)d_in[19];
  const float* nln2_b = (const float*)d_in[20];

  // workspace layout (floats); total ~108.9 MB
  float*  ws     = (float*)d_ws;
  float*  xbuf   = ws;                                   // 3,145,728 fl
  ushort* bufCs  = (ushort*)(xbuf + 3145728);            // 3,763,200 sh
  float*  bufD   = xbuf + 3145728 + 1881600;             // 3,763,200 fl
  float*  bufQE  = bufD + 3763200;                       // 11,289,600 fl
  ushort* bufQEs = (ushort*)bufQE;
  ushort* rhB    = (ushort*)(bufQE + 11289600);          // 3,145,728 sh
  ushort* rwB    = rhB + 3145728;                        // 3,145,728 sh
  ushort* wqT    = rwB + 3145728;                        // 1,769,472 sh
  ushort* wpT    = wqT + 1769472;                        //   589,824 sh
  ushort* wf1T   = wpT + 589824;                         // 2,359,296 sh
  ushort* wf2T   = wf1T + 2359296;                       // 2,359,296 sh
  ushort* wnT    = wf2T + 2359296;                       //   196,608 sh
  ushort* wn2T   = wnT + 196608;                         //   589,824 sh
  ushort* bufDs  = (ushort*)bufD;                        // also hosts VT during attention

  copy4_kernel<<<CDIV(786432,256),256,0,stream>>>((float4*)xbuf, (const float4*)x_in, 786432);

  for (int i = 0; i < 4; ++i) {
    int wsz = (i < 3) ? 14 : 0;
    transpose_cvt_kernel<<<dim3(2304/32, 768/32),256,0,stream>>>(qkv_w + (size_t)i*768*2304, wqT, 768, 2304);
    transpose_cvt_kernel<<<dim3(768/32,  768/32),256,0,stream>>>(proj_w + (size_t)i*768*768,  wpT, 768, 768);
    transpose_cvt_kernel<<<dim3(3072/32, 768/32),256,0,stream>>>(fc1_w + (size_t)i*768*3072, wf1T, 768, 3072);
    transpose_cvt_kernel<<<dim3(768/32, 3072/32),256,0,stream>>>(fc2_w + (size_t)i*3072*768, wf2T, 3072, 768);

    ln_kernel<<<1024,256,0,stream>>>(xbuf, ln1_g + i*768, ln1_b + i*768, nullptr, bufCs, 768, 1e-5f, 4096);
    int M;
    const ushort* qkvIn;
    int nWin, T, S;
    if (wsz > 0) {
      winpart_kernel<<<CDIV(25*196*96,256),256,0,stream>>>(bufCs, bufDs);
      qkvIn = bufDs; M = 4900; nWin = 25; T = 196; S = 14;
    } else {
      qkvIn = bufCs; M = 4096; nWin = 1; T = 4096; S = 64;
    }
    gemm_bf16_kernel<128,128><<<dim3(2304/128, CDIV(M,128)),256,0,stream>>>(
        qkvIn, wqT, qkv_b + i*2304, nullptr, nullptr, bufQEs, M, 2304, 768, 0);
    int relTot = nWin*12*T*S;
    relbias_kernel<<<CDIV(relTot,256),256,0,stream>>>(bufQEs, rel_h + i*127*64, rhB, nWin, T, S, 1);
    relbias_kernel<<<CDIV(relTot,256),256,0,stream>>>(bufQEs, rel_w + i*127*64, rwB, nWin, T, S, 0);
    if (wsz > 0) {
      vtrans_kernel<<<dim3(4, 300),256,0,stream>>>(bufQEs, bufDs, 196, 256, 0);
      attn3_kernel<14><<<dim3(4,12,25),256,0,stream>>>(bufQEs, rhB, rwB, bufDs, bufCs, 196);
    } else {
      vtrans_kernel<<<dim3(64, 12),256,0,stream>>>(bufQEs, bufDs, 4096, 4096, 1);
      attn4_kernel<<<dim3(64,12),256,0,stream>>>(bufQEs, rhB, rwB, bufDs, bufCs);
    }
    gemm_bf16_kernel<64,128><<<dim3(768/128, CDIV(M,64)),256,0,stream>>>(
        bufCs, wpT, proj_b + i*768, nullptr, bufD, nullptr, M, 768, 768, 0);
    if (wsz > 0)
      unpart_add_kernel<<<CDIV(4096*192,256),256,0,stream>>>(xbuf, bufD);
    else
      add4_kernel<<<CDIV(786432,256),256,0,stream>>>((float4*)xbuf, (const float4*)bufD, 786432);
    // MLP
    ln_kernel<<<1024,256,0,stream>>>(xbuf, ln2_g + i*768, ln2_b + i*768, nullptr, bufCs, 768, 1e-5f, 4096);
    gemm_bf16_kernel<128,128><<<dim3(3072/128, 4096/128),256,0,stream>>>(
        bufCs, wf1T, fc1_b + i*3072, nullptr, nullptr, bufQEs, 4096, 3072, 768, 1);
    gemm_bf16_kernel<64,128><<<dim3(768/128, 4096/64),256,0,stream>>>(
        bufQEs, wf2T, fc2_b + i*768, xbuf, xbuf, (i==3) ? bufCs : nullptr, 4096, 768, 3072, 0);
  }

  // neck
  transpose_cvt_kernel<<<dim3(256/32, 768/32),256,0,stream>>>(nconv1, wnT, 768, 256);
  transpose_cvt_kernel<<<dim3(256/32, 2304/32),256,0,stream>>>(nconv2, wn2T, 2304, 256);
  gemm_bf16_kernel<64,64><<<dim3(256/64, 4096/64),256,0,stream>>>(
      bufCs, wnT, nullptr, nullptr, bufD, nullptr, 4096, 256, 768, 0);
  ln_kernel<<<1024,256,0,stream>>>(bufD, nln1_g, nln1_b, nullptr, bufCs, 256, 1e-6f, 4096);
  im2col3_kernel<<<CDIV(4096*288,256),256,0,stream>>>(bufCs, bufQEs);
  gemm_bf16_kernel<64,64><<<dim3(256/64, 4096/64),256,0,stream>>>(
      bufQEs, wn2T, nullptr, nullptr, bufD, nullptr, 4096, 256, 2304, 0);
  ln_kernel<<<1024,256,0,stream>>>(bufD, nln2_g, nln2_b, bufQE, nullptr, 256, 1e-6f, 4096);
  transpose_f32_kernel<<<dim3(256/32, 4096/32),256,0,stream>>>(bufQE, (float*)d_out, 4096, 256);
}

// Round 8
// 1720.996 us; speedup vs baseline: 1.0064x; 1.0064x over previous
//
#include <hip/hip_runtime.h>
#include <math.h>

#define CDIV(a,b) (((a)+(b)-1)/(b))

typedef __attribute__((ext_vector_type(8))) short short8v;   // 8 bf16 = 4 VGPRs
typedef __attribute__((ext_vector_type(4))) float float4v;

__device__ __forceinline__ ushort f2b(float f) {
  union { float f; unsigned u; } v; v.f = f;
  unsigned r = (v.u + 0x7fffu + ((v.u >> 16) & 1u)) >> 16;   // RNE
  return (ushort)r;
}
__device__ __forceinline__ float b2f(ushort h) {
  union { unsigned u; float f; } v; v.u = ((unsigned)h) << 16;
  return v.f;
}

// async global->LDS, 16B per lane; lds base must be wave-uniform (HW adds lane*16)
__device__ __forceinline__ void gload_lds16(const ushort* g, ushort* l) {
  __builtin_amdgcn_global_load_lds(
      (const __attribute__((address_space(1))) void*)g,
      (__attribute__((address_space(3))) void*)l, 16, 0, 0);
}

// ---------------------------------------------------------------- elementwise (vectorized)
__global__ __launch_bounds__(256) void copy4_kernel(float4* __restrict__ dst,
                                                    const float4* __restrict__ src, int n4) {
  int i = blockIdx.x*256 + threadIdx.x;
  if (i < n4) dst[i] = src[i];
}

__global__ __launch_bounds__(256) void add4_kernel(float4* __restrict__ x,
                                                   const float4* __restrict__ y, int n4) {
  int i = blockIdx.x*256 + threadIdx.x;
  if (i >= n4) return;
  float4 a = x[i], b = y[i];
  a.x += b.x; a.y += b.y; a.z += b.z; a.w += b.w;
  x[i] = a;
}

// ---------------------------------------------------------------- LayerNorm, one wave per row
__global__ __launch_bounds__(256) void ln_kernel(const float* __restrict__ in,
    const float* __restrict__ g, const float* __restrict__ b,
    float* __restrict__ outf, ushort* __restrict__ outb, int C, float eps, int nrows)
{
  int row = blockIdx.x*4 + (threadIdx.x >> 6);
  int lane = threadIdx.x & 63;
  if (row >= nrows) return;
  const float* rp = in + (size_t)row*C;
  float s = 0.f, s2 = 0.f;
  for (int c = lane; c < C; c += 64) { float v = rp[c]; s += v; s2 += v*v; }
  #pragma unroll
  for (int off = 32; off > 0; off >>= 1) { s += __shfl_xor(s, off); s2 += __shfl_xor(s2, off); }
  float mean = s / C;
  float var  = s2 / C - mean*mean;
  float inv  = rsqrtf(var + eps);
  for (int c = lane; c < C; c += 64) {
    float v = (rp[c]-mean)*inv*g[c] + b[c];
    if (outb) outb[(size_t)row*C + c] = f2b(v);
    else      outf[(size_t)row*C + c] = v;
  }
}

// ---------------------------------------------------------------- window partition (bf16, 8-wide)
__global__ __launch_bounds__(256) void winpart_kernel(const ushort* __restrict__ in,
                                                      ushort* __restrict__ out) {
  int i = blockIdx.x*256 + threadIdx.x;          // over 25*196*96 uint4 units
  if (i >= 25*196*96) return;
  int c8 = i % 96; int t = (i / 96) % 196; int b = i / (96*196);
  int wy = b / 5, wx = b % 5;
  int iy = t / 14, ix = t % 14;
  int h = wy*14 + iy, w = wx*14 + ix;
  uint4 v = {0u,0u,0u,0u};
  if (h < 64 && w < 64) v = *(const uint4*)(in + ((size_t)(h*64 + w))*768 + c8*8);
  *(uint4*)(out + (size_t)i*8) = v;
}

// window unpartition + residual add (float4)
__global__ __launch_bounds__(256) void unpart_add_kernel(float* __restrict__ x,
                                                         const float* __restrict__ p) {
  int i = blockIdx.x*256 + threadIdx.x;          // over 4096*192 float4 units
  if (i >= 4096*192) return;
  int c4 = i % 192; int hw = i / 192; int w = hw % 64; int h = hw / 64;
  int wy = h/14, iy = h%14, wx = w/14, ix = w%14;
  int b = wy*5 + wx; int t = iy*14 + ix;
  float4 a = *(const float4*)(x + (size_t)i*4);
  float4 r = *(const float4*)(p + ((size_t)(b*196 + t))*768 + c4*4);
  a.x += r.x; a.y += r.y; a.z += r.z; a.w += r.w;
  *(float4*)(x + (size_t)i*4) = a;
}

// ---------------------------------------------------------------- weight transpose+convert: in [K][N] f32 -> out [N][K] bf16
__global__ __launch_bounds__(256) void transpose_cvt_kernel(const float* __restrict__ in,
    ushort* __restrict__ out, int K, int N)
{
  __shared__ float t[32][33];
  int n0 = blockIdx.x*32, k0 = blockIdx.y*32;
  int cc = threadIdx.x & 31, rr = threadIdx.x >> 5;
  for (int r = rr; r < 32; r += 8) t[r][cc] = in[(size_t)(k0+r)*N + n0 + cc];
  __syncthreads();
  for (int r = rr; r < 32; r += 8) out[(size_t)(n0+r)*K + k0 + cc] = f2b(t[cc][r]);
}

// f32 transpose: in [R][Cc] -> out [Cc][R]  (for NHWC->NCHW)
__global__ __launch_bounds__(256) void transpose_f32_kernel(const float* __restrict__ in,
    float* __restrict__ out, int R, int Cc)
{
  __shared__ float t[32][33];
  int c0 = blockIdx.x*32, r0 = blockIdx.y*32;
  int cc = threadIdx.x & 31, rr = threadIdx.x >> 5;
  for (int r = rr; r < 32; r += 8) t[r][cc] = in[(size_t)(r0+r)*Cc + c0 + cc];
  __syncthreads();
  for (int r = rr; r < 32; r += 8) out[(size_t)(c0+r)*R + r0 + cc] = t[cc][r];
}

// ---------------------------------------------------------------- V transpose: qkv v-slice -> vt[wn][64 dim][strideV keys] bf16
// perm!=0: within each 64-key tile, physical column p holds key (p&3)*16 + (p>>2)
// (matches attn4's packed-b64 P layout; PV sum is permutation-invariant)
__global__ __launch_bounds__(256) void vtrans_kernel(const ushort* __restrict__ qkv,
    ushort* __restrict__ vt, int T, int strideV, int perm)
{
  __shared__ ushort tile[64*72];
  int kt = blockIdx.x, wn = blockIdx.y;
  int win = wn / 12, n = wn - win*12;
  int tid = threadIdx.x;
  size_t tokBase = (size_t)win * T;
  int k0 = kt*64;
  #pragma unroll
  for (int it=0; it<2; ++it) {
    int id = tid + it*256;
    int r = id >> 3, ch = id & 7;
    int kk = k0 + r; if (kk >= T) kk = T-1;
    *(uint4*)(tile + r*72 + ch*8) =
      *(const uint4*)(qkv + (tokBase + kk)*2304 + 1536 + n*64 + ch*8);
  }
  __syncthreads();
  #pragma unroll
  for (int it=0; it<2; ++it) {
    int id = tid + it*256;
    int d = id & 63, kg = id >> 6;     // kg 0..7
    union { uint4 v; ushort u[8]; } o;
    #pragma unroll
    for (int j=0;j<8;++j) {
      int p = kg*8 + j;
      int kl = perm ? ((p & 3)*16 + (p >> 2)) : p;
      o.u[j] = tile[kl*72 + d];
    }
    *(uint4*)(vt + ((size_t)wn*64 + d)*strideV + k0 + kg*8) = o.v;
  }
}

// ---------------------------------------------------------------- bf16 MFMA GEMM
// m97 structure + bijective XCD swizzle (m204), templated tile:
//   <128,128>: 2x2 waves, 64x64/wave (original)
//   <64,128>:  1x4 waves, 64x32/wave  (narrow-N: proj, fc2 — doubles grid)
//   <64,64>:   1x4 waves, 64x16/wave  (neck convs — 4x grid)
// Staging: (BM+BN)/16 16-row DMA slots round-robin over 4 waves (all configs divide).
template<int BM, int BN>
__global__ __launch_bounds__(256) void gemm_bf16_kernel(
    const ushort* __restrict__ A, const ushort* __restrict__ Bt,
    const float* __restrict__ bias, const float* __restrict__ res,
    float* __restrict__ Cf, ushort* __restrict__ Cb,
    int M, int N, int K, int act)
{
  constexpr int WMW = (BM == 128) ? 2 : 1;   // waves along M
  constexpr int WNW = 4 / WMW;               // waves along N
  constexpr int MI  = BM / (WMW*16);
  constexpr int NI  = BN / (WNW*16);
  constexpr int ASLOTS = BM/16;
  constexpr int TSLOTS = (BM+BN)/16;
  constexpr int NSLOT  = TSLOTS/4;           // per-wave DMA slots

  __shared__ ushort Al[BM*32];
  __shared__ ushort Bl[BN*32];
  int tid = threadIdx.x;
  int lane = tid & 63, wave = tid >> 6;
  int wm = (WMW==2) ? (wave & 1) : 0;
  int wn = (WMW==2) ? (wave >> 1) : wave;
  int l15 = lane & 15, lq = lane >> 4;

  // bijective XCD-aware remap (m204)
  int gx = gridDim.x;
  int nwg = gx * gridDim.y;
  int orig = blockIdx.y * gx + blockIdx.x;
  int q8 = nwg >> 3, r8 = nwg & 7;
  int xcd = orig & 7, within = orig >> 3;
  int lin = (xcd < r8 ? xcd*(q8+1) : r8*(q8+1) + (xcd-r8)*q8) + within;
  int bx = lin % gx, by = lin / gx;

  int rowBase = by * BM, colBase = bx * BN;
  float4v acc[MI][NI];
  #pragma unroll
  for (int i=0;i<MI;++i)
    #pragma unroll
    for (int j=0;j<NI;++j) acc[i][j] = (float4v){0.f,0.f,0.f,0.f};

  int cs  = (lane&3) ^ ((lane>>3)&3);   // staged source chunk (XOR key = (row>>1)&3)
  int rsl = lane >> 2;                  // row within 16-row slot

  const ushort* gsrc[NSLOT];
  ushort* ldst[NSLOT];
  #pragma unroll
  for (int s=0; s<NSLOT; ++s) {
    int ls = wave + 4*s;
    if (ls < ASLOTS) {
      int gr = rowBase + ls*16 + rsl; if (gr >= M) gr = M-1;
      gsrc[s] = A + (size_t)gr*K + cs*8;
      ldst[s] = Al + (ls*16)*32;
    } else {
      int lb = ls - ASLOTS;
      int gc = colBase + lb*16 + rsl;          // N % BN == 0 at all call sites
      gsrc[s] = Bt + (size_t)gc*K + cs*8;
      ldst[s] = Bl + (lb*16)*32;
    }
  }

  int sA = (l15 >> 1) & 3;
  int rdOff = ((lq ^ sA) << 3);

  for (int k0 = 0; k0 < K; k0 += 32) {
    __syncthreads();
    #pragma unroll
    for (int s=0; s<NSLOT; ++s) gload_lds16(gsrc[s] + k0, ldst[s]);
    __syncthreads();
    short8v af[MI], bf[NI];
    #pragma unroll
    for (int mi=0; mi<MI; ++mi)
      af[mi] = *(const short8v*)(Al + (wm*(BM/WMW) + mi*16 + l15)*32 + rdOff);
    #pragma unroll
    for (int ni=0; ni<NI; ++ni)
      bf[ni] = *(const short8v*)(Bl + (wn*(BN/WNW) + ni*16 + l15)*32 + rdOff);
    #pragma unroll
    for (int mi=0; mi<MI; ++mi)
      #pragma unroll
      for (int ni=0; ni<NI; ++ni)
        acc[mi][ni] = __builtin_amdgcn_mfma_f32_16x16x32_bf16(af[mi], bf[ni], acc[mi][ni], 0, 0, 0);
  }
  #pragma unroll
  for (int mi=0; mi<MI; ++mi) {
    int gr0e = rowBase + wm*(BM/WMW) + mi*16 + lq*4;
    #pragma unroll
    for (int ni=0; ni<NI; ++ni) {
      int gc = colBase + wn*(BN/WNW) + ni*16 + l15;
      float bsv = bias ? bias[gc] : 0.f;
      #pragma unroll
      for (int r=0; r<4; ++r) {
        int gr = gr0e + r;
        if (gr < M) {
          float v = acc[mi][ni][r] + bsv;
          if (act) v = 0.5f*v*(1.f + erff(v*0.70710678118f));
          if (res) v += res[(size_t)gr*N + gc];
          if (Cf) Cf[(size_t)gr*N + gc] = v;
          if (Cb) Cb[(size_t)gr*N + gc] = f2b(v);
        }
      }
    }
  }
}

// ---------------------------------------------------------------- im2col for 3x3 SAME conv, bf16, 64x64x256
__global__ __launch_bounds__(256) void im2col3_kernel(const ushort* __restrict__ in,
                                                      ushort* __restrict__ out)
{
  int gid = blockIdx.x*256 + threadIdx.x;      // over 4096*288 uint4 units
  if (gid >= 4096*288) return;
  int u = gid % 288;  int p = gid / 288;
  int x = p & 63, y = p >> 6;
  int tap = u >> 5;
  int cu  = u & 31;
  int dy = tap / 3, dx = tap - dy*3;
  int yy = y + dy - 1, xx = x + dx - 1;
  uint4 v = {0u,0u,0u,0u};
  if (yy >= 0 && yy < 64 && xx >= 0 && xx < 64)
    v = *(const uint4*)(in + ((size_t)(yy*64 + xx))*256 + cu*8);
  *(uint4*)(out + (size_t)p*2304 + u*8) = v;
}

// ---------------------------------------------------------------- decomposed rel-pos bias (bf16 qkv in, bf16 out)
// v9: vectorized loads (short8 q, float4 table) — G13; fma chain order preserved
// exactly (s0 over even d, s1 over odd d, ascending) -> bit-identical output.
__global__ __launch_bounds__(256) void relbias_kernel(const ushort* __restrict__ qkv,
    const float* __restrict__ table, ushort* __restrict__ out,
    int nWin, int T, int S, int useH)
{
  int gid = blockIdx.x*256 + threadIdx.x;
  int total = nWin*12*T*S;
  if (gid >= total) return;
  int kk = gid % S; int r = gid / S;
  int t = r % T; int r2 = r / T; int n = r2 % 12; int b = r2 / 12;
  int coord = useH ? (t / S) : (t % S);
  const ushort* q = qkv + ((size_t)(b*T + t))*2304 + n*64;
  const float* tb = table + (size_t)(coord - kk + S - 1)*64;
  float s0=0.f, s1=0.f;
  #pragma unroll
  for (int d8=0; d8<8; ++d8) {
    short8v qv = *(const short8v*)(q + d8*8);
    float4 ta = *(const float4*)(tb + d8*8);
    float4 tc = *(const float4*)(tb + d8*8 + 4);
    s0 = fmaf(b2f((ushort)qv[0]), ta.x, s0);
    s1 = fmaf(b2f((ushort)qv[1]), ta.y, s1);
    s0 = fmaf(b2f((ushort)qv[2]), ta.z, s0);
    s1 = fmaf(b2f((ushort)qv[3]), ta.w, s1);
    s0 = fmaf(b2f((ushort)qv[4]), tc.x, s0);
    s1 = fmaf(b2f((ushort)qv[5]), tc.y, s1);
    s0 = fmaf(b2f((ushort)qv[6]), tc.z, s0);
    s1 = fmaf(b2f((ushort)qv[7]), tc.w, s1);
  }
  out[gid] = f2b(s0 + s1);
}

// ---------------------------------------------------------------- MFMA flash attention (windowed)
// Fixed-max softmax (M0=8 folded into RWl), deferred l-reduce, pre-transposed V.
template<int S>
__global__ __launch_bounds__(256) void attn3_kernel(
    const ushort* __restrict__ qkv, const ushort* __restrict__ rh,
    const ushort* __restrict__ rw, const ushort* __restrict__ vtw,
    ushort* __restrict__ outb, int T)
{
  constexpr int SP = (S + 15) & ~15;
  __shared__ ushort Ql[64*72];
  __shared__ ushort Kl[64*72];
  __shared__ ushort Vt[64*72];
  __shared__ ushort Pl[64*72];
  __shared__ ushort RHl[64*SP];
  __shared__ ushort RWl[64*SP];

  int qt = blockIdx.x, n = blockIdx.y, b = blockIdx.z;
  int wn = b*12 + n;
  int tid = threadIdx.x, lane = tid & 63, w = tid >> 6;
  int l15 = lane & 15, lq = lane >> 4;
  size_t tokBase = (size_t)b * T;
  int q0 = qt * 64;

  #pragma unroll
  for (int it = 0; it < 2; ++it) {
    int id = tid + it*256;
    int r = id >> 3, ch = id & 7;
    int qq = q0 + r; if (qq >= T) qq = T - 1;
    *(uint4*)(Ql + r*72 + ch*8) =
        *(const uint4*)(qkv + (tokBase + qq)*2304 + n*64 + ch*8);
  }
  for (int idx = tid; idx < 64*S; idx += 256) {
    int r = idx / S, c = idx - r*S;
    int qq = q0 + r; if (qq >= T) qq = T - 1;
    size_t base = ((size_t)(b*12 + n)*T + qq)*S;
    RHl[r*SP + c] = rh[base + c];
    RWl[r*SP + c] = f2b(b2f(rw[base + c]) - 8.0f);   // fold fixed max
  }
  __syncthreads();
  short8v aq0 = *(const short8v*)(Ql + (w*16 + l15)*72 + lq*8);
  short8v aq1 = *(const short8v*)(Ql + (w*16 + l15)*72 + 32 + lq*8);

  float lacc[4] = {0.f,0.f,0.f,0.f};
  float4v O[4];
  #pragma unroll
  for (int i=0;i<4;++i) O[i] = (float4v){0.f,0.f,0.f,0.f};

  int nkt = (T + 63) >> 6;
  for (int kt = 0; kt < nkt; ++kt) {
    int k0 = kt*64;
    __syncthreads();
    #pragma unroll
    for (int it=0; it<2; ++it) {
      int id = tid + it*256;
      int r = id >> 3, ch = id & 7;
      int kk = k0 + r; if (kk >= T) kk = T-1;
      *(uint4*)(Kl + r*72 + ch*8) =
        *(const uint4*)(qkv + (tokBase + kk)*2304 + 768 + n*64 + ch*8);
      *(uint4*)(Vt + r*72 + ch*8) =
        *(const uint4*)(vtw + ((size_t)wn*64 + r)*256 + k0 + ch*8);
    }
    __syncthreads();

    float4v Sv[4];
    #pragma unroll
    for (int ni=0; ni<4; ++ni) {
      short8v bk0 = *(const short8v*)(Kl + (ni*16 + l15)*72 + lq*8);
      short8v bk1 = *(const short8v*)(Kl + (ni*16 + l15)*72 + 32 + lq*8);
      float4v s = (float4v){0.f,0.f,0.f,0.f};
      s = __builtin_amdgcn_mfma_f32_16x16x32_bf16(aq0, bk0, s, 0,0,0);
      s = __builtin_amdgcn_mfma_f32_16x16x32_bf16(aq1, bk1, s, 0,0,0);
      Sv[ni] = s;
    }

    #pragma unroll
    for (int r=0;r<4;++r) {
      int qlrow = w*16 + lq*4 + r;
      #pragma unroll
      for (int ni=0;ni<4;++ni) {
        int key = k0 + ni*16 + l15;
        int kcl = key < T ? key : 0;
        int kh = kcl / S, kw = kcl - kh*S;
        float sc = key < T
          ? fmaf(Sv[ni][r], 0.125f, b2f(RHl[qlrow*SP+kh]) + b2f(RWl[qlrow*SP+kw]))
          : -1e30f;
        float pv = __expf(sc);
        lacc[r] += pv;
        union { float f; unsigned u; } cv; cv.f = pv;
        Pl[qlrow*72 + ni*16 + l15] = (ushort)((cv.u + 0x8000u) >> 16);
      }
    }

    short8v ap0 = *(const short8v*)(Pl + (w*16 + l15)*72 + lq*8);
    short8v ap1 = *(const short8v*)(Pl + (w*16 + l15)*72 + 32 + lq*8);
    #pragma unroll
    for (int ni=0;ni<4;++ni) {
      short8v bv0 = *(const short8v*)(Vt + (ni*16 + l15)*72 + lq*8);
      short8v bv1 = *(const short8v*)(Vt + (ni*16 + l15)*72 + 32 + lq*8);
      O[ni] = __builtin_amdgcn_mfma_f32_16x16x32_bf16(ap0, bv0, O[ni], 0,0,0);
      O[ni] = __builtin_amdgcn_mfma_f32_16x16x32_bf16(ap1, bv1, O[ni], 0,0,0);
    }
  }

  #pragma unroll
  for (int r=0;r<4;++r) {
    int qlrow = w*16 + lq*4 + r;
    int qg = q0 + qlrow;
    float ls = lacc[r];
    #pragma unroll
    for (int off=1; off<16; off<<=1) ls += __shfl_xor(ls, off);
    if (qg < T) {
      float inv = 1.f / ls;
      #pragma unroll
      for (int ni=0;ni<4;++ni)
        outb[(tokBase + qg)*768 + n*64 + ni*16 + l15] = f2b(O[ni][r]*inv);
    }
  }
}

// ---------------------------------------------------------------- specialized global flash attention (T=4096, S=64)
// v6 structure (best measured: 117.9us): DMA-staged double-buffered K/V, one
// barrier/tile, Q direct-to-reg, wave-private RH/P, packed ds_write_b64 P with
// permuted V cols. (v8's inline-asm cvt_pk + exp2 trim REGRESSED — reverted.)
__global__ __launch_bounds__(256) void attn4_kernel(
    const ushort* __restrict__ qkv, const ushort* __restrict__ rh,
    const ushort* __restrict__ rw, const ushort* __restrict__ vtg,
    ushort* __restrict__ outb)
{
  const int T = 4096;
  __shared__ ushort Kl[2][64*64];     // linear rows (128B); phys chunk c holds logical chunk c^(row&7)
  __shared__ ushort Vl[2][64*64];
  __shared__ ushort Pl[64*64];        // wave-private rows, same chunk swizzle
  __shared__ ushort RHl[64*72];       // stride 72 (144B, 16B-aligned rows)

  int qt = blockIdx.x, n = blockIdx.y;
  int tid = threadIdx.x, lane = tid & 63, w = tid >> 6;
  int l15 = lane & 15, lq = lane >> 4;
  int q0 = qt * 64;

  // RH rows, wave-private mapping: wave w stages exactly rows w*16..w*16+15
  #pragma unroll
  for (int it = 0; it < 2; ++it) {
    int id2 = lane + it*64;
    int r = w*16 + (id2 >> 3), ch = id2 & 7;
    *(uint4*)(RHl + r*72 + ch*8) =
        *(const uint4*)(rh + ((size_t)n*T + q0 + r)*64 + ch*8);
  }
  // Q fragments straight from global (one-shot, no LDS round-trip)
  const ushort* qp = qkv + (size_t)(q0 + w*16 + l15)*2304 + n*64 + lq*8;
  short8v aq0 = *(const short8v*)(qp);
  short8v aq1 = *(const short8v*)(qp + 32);

  // preload this lane's rw values (kw fixed across tiles), fold fixed max -8
  float rwp[4][4];
  #pragma unroll
  for (int r=0;r<4;++r)
    #pragma unroll
    for (int ni=0;ni<4;++ni)
      rwp[r][ni] = b2f(rw[((size_t)n*T + q0 + w*16 + lq*4 + r)*64 + ni*16 + l15]) - 8.0f;

  const ushort* kbase = qkv + 768 + n*64;          // + row*2304
  const ushort* vbase = vtg + (size_t)n*64*4096;   // [dim][keypos] (columns tile-permuted)
  int sr  = (lane >> 3) & 7;                       // staged row-within-8
  int sch = lane & 7;                              // staged (physical) chunk = lane&7
  int swz = ((sch ^ sr) << 3);                     // inverse-swizzled logical source chunk (ushorts)

  // per wave: 4 DMA loads/tile (2 K + 2 V), rows w*16..w*16+15, LDS dest linear
  auto stage = [&](int buf, int k0s) {
    #pragma unroll
    for (int it=0; it<2; ++it) {
      int rr = w*16 + it*8 + sr;
      gload_lds16(kbase + (size_t)(k0s + rr)*2304 + swz, &Kl[buf][(w*2+it)*512]);
      gload_lds16(vbase + (size_t)rr*4096 + k0s + swz, &Vl[buf][(w*2+it)*512]);
    }
  };

  float lacc[4] = {0.f,0.f,0.f,0.f};
  float4v O[4];
  #pragma unroll
  for (int i=0;i<4;++i) O[i] = (float4v){0.f,0.f,0.f,0.f};

  stage(0, 0);

  int xk  = (lq ^ (l15 & 7)) << 3;          // chunk lq   swizzled read offset (ushorts)
  int xk4 = ((lq ^ 4) ^ (l15 & 7)) << 3;    // chunk lq+4 swizzled

  for (int kt = 0; kt < 64; ++kt) {
    int cur = kt & 1;
    __syncthreads();
    if (kt < 63) stage(cur ^ 1, (kt+1)*64);

    const ushort* Kc = Kl[cur];
    const ushort* Vc = Vl[cur];

    float4v Sv[4];
    #pragma unroll
    for (int ni=0; ni<4; ++ni) {
      short8v bk0 = *(const short8v*)(Kc + (ni*16 + l15)*64 + xk);
      short8v bk1 = *(const short8v*)(Kc + (ni*16 + l15)*64 + xk4);
      float4v s = (float4v){0.f,0.f,0.f,0.f};
      s = __builtin_amdgcn_mfma_f32_16x16x32_bf16(aq0, bk0, s, 0,0,0);
      s = __builtin_amdgcn_mfma_f32_16x16x32_bf16(aq1, bk1, s, 0,0,0);
      Sv[ni] = s;
    }

    // softmax (fixed max, deferred l) + packed P write:
    // physical key position p = l15*4 + ni; V columns hold key (p&3)*16+(p>>2) = ni*16+l15
    #pragma unroll
    for (int r=0;r<4;++r) {
      int qlrow = w*16 + lq*4 + r;
      float rhv = b2f(RHl[qlrow*72 + kt]);           // broadcast per lq-group
      union { unsigned long long u; ushort us[4]; } pk;
      #pragma unroll
      for (int ni=0;ni<4;++ni) {
        float pv = __expf(fmaf(Sv[ni][r], 0.125f, rhv + rwp[r][ni]));
        lacc[r] += pv;
        union { float f; unsigned u; } cv; cv.f = pv;
        pk.us[ni] = (ushort)((cv.u + 0x8000u) >> 16);
      }
      *(unsigned long long*)(Pl + qlrow*64 +
          ((((l15 >> 1)) ^ (qlrow & 7)) << 3) + (l15 & 1)*4) = pk.u;
    }

    // P rows are wave-private -> no barrier needed between write and read
    short8v ap0 = *(const short8v*)(Pl + (w*16 + l15)*64 + xk);
    short8v ap1 = *(const short8v*)(Pl + (w*16 + l15)*64 + xk4);
    #pragma unroll
    for (int ni=0;ni<4;++ni) {
      short8v bv0 = *(const short8v*)(Vc + (ni*16 + l15)*64 + xk);
      short8v bv1 = *(const short8v*)(Vc + (ni*16 + l15)*64 + xk4);
      O[ni] = __builtin_amdgcn_mfma_f32_16x16x32_bf16(ap0, bv0, O[ni], 0,0,0);
      O[ni] = __builtin_amdgcn_mfma_f32_16x16x32_bf16(ap1, bv1, O[ni], 0,0,0);
    }
  }

  #pragma unroll
  for (int r=0;r<4;++r) {
    int qg = q0 + w*16 + lq*4 + r;
    float ls = lacc[r];
    #pragma unroll
    for (int off=1; off<16; off<<=1) ls += __shfl_xor(ls, off);
    float inv = 1.f / ls;
    #pragma unroll
    for (int ni=0;ni<4;++ni)
      outb[(size_t)qg*768 + n*64 + ni*16 + l15] = f2b(O[ni][r]*inv);
  }
}

// ================================================================ launch
extern "C" void kernel_launch(void* const* d_in, const int* in_sizes, int n_in,
                              void* d_out, int out_size, void* d_ws, size_t ws_size,
                              hipStream_t stream)
{
  const float* x_in   = (const float*)d_in[0];
  const float* ln1_g  = (const float*)d_in[1];
  const float* ln1_b  = (const float*)d_in[2];
  const float* qkv_w  = (const float*)d_in[3];
  const float* qkv_b  = (const float*)d_in[4];
  const float* proj_w = (const float*)d_in[5];
  const float* proj_b = (const float*)d_in[6];
  const float* rel_h  = (const float*)d_in[7];
  const float* rel_w  = (const float*)d_in[8];
  const float* ln2_g  = (const float*)d_in[9];
  const float* ln2_b  = (const float*)d_in[10];
  const float* fc1_w  = (const float*)d_in[11];
  const float* fc1_b  = (const float*)d_in[12];
  const float* fc2_w  = (const float*)d_in[13];
  const float* fc2_b  = (const float*)d_in[14];
  const float* nconv1 = (const float*)d_in[15];
  const float* nln1_g = (const float*)d_in[16];
  const float* nln1_b = (const float*)d_in[17];
  const float* nconv2 = (const float*)d_in[18];
  const float* nln2_g = (const float*)d_in[19];
  const float* nln2_b = (const float*)d_in[20];

  // workspace layout (floats); total ~108.9 MB
  float*  ws     = (float*)d_ws;
  float*  xbuf   = ws;                                   // 3,145,728 fl
  ushort* bufCs  = (ushort*)(xbuf + 3145728);            // 3,763,200 sh
  float*  bufD   = xbuf + 3145728 + 1881600;             // 3,763,200 fl
  float*  bufQE  = bufD + 3763200;                       // 11,289,600 fl
  ushort* bufQEs = (ushort*)bufQE;
  ushort* rhB    = (ushort*)(bufQE + 11289600);          // 3,145,728 sh
  ushort* rwB    = rhB + 3145728;                        // 3,145,728 sh
  ushort* wqT    = rwB + 3145728;                        // 1,769,472 sh
  ushort* wpT    = wqT + 1769472;                        //   589,824 sh
  ushort* wf1T   = wpT + 589824;                         // 2,359,296 sh
  ushort* wf2T   = wf1T + 2359296;                       // 2,359,296 sh
  ushort* wnT    = wf2T + 2359296;                       //   196,608 sh
  ushort* wn2T   = wnT + 196608;                         //   589,824 sh
  ushort* bufDs  = (ushort*)bufD;                        // also hosts VT during attention

  copy4_kernel<<<CDIV(786432,256),256,0,stream>>>((float4*)xbuf, (const float4*)x_in, 786432);

  for (int i = 0; i < 4; ++i) {
    int wsz = (i < 3) ? 14 : 0;
    transpose_cvt_kernel<<<dim3(2304/32, 768/32),256,0,stream>>>(qkv_w + (size_t)i*768*2304, wqT, 768, 2304);
    transpose_cvt_kernel<<<dim3(768/32,  768/32),256,0,stream>>>(proj_w + (size_t)i*768*768,  wpT, 768, 768);
    transpose_cvt_kernel<<<dim3(3072/32, 768/32),256,0,stream>>>(fc1_w + (size_t)i*768*3072, wf1T, 768, 3072);
    transpose_cvt_kernel<<<dim3(768/32, 3072/32),256,0,stream>>>(fc2_w + (size_t)i*3072*768, wf2T, 3072, 768);

    ln_kernel<<<1024,256,0,stream>>>(xbuf, ln1_g + i*768, ln1_b + i*768, nullptr, bufCs, 768, 1e-5f, 4096);
    int M;
    const ushort* qkvIn;
    int nWin, T, S;
    if (wsz > 0) {
      winpart_kernel<<<CDIV(25*196*96,256),256,0,stream>>>(bufCs, bufDs);
      qkvIn = bufDs; M = 4900; nWin = 25; T = 196; S = 14;
    } else {
      qkvIn = bufCs; M = 4096; nWin = 1; T = 4096; S = 64;
    }
    gemm_bf16_kernel<128,128><<<dim3(2304/128, CDIV(M,128)),256,0,stream>>>(
        qkvIn, wqT, qkv_b + i*2304, nullptr, nullptr, bufQEs, M, 2304, 768, 0);
    int relTot = nWin*12*T*S;
    relbias_kernel<<<CDIV(relTot,256),256,0,stream>>>(bufQEs, rel_h + i*127*64, rhB, nWin, T, S, 1);
    relbias_kernel<<<CDIV(relTot,256),256,0,stream>>>(bufQEs, rel_w + i*127*64, rwB, nWin, T, S, 0);
    if (wsz > 0) {
      vtrans_kernel<<<dim3(4, 300),256,0,stream>>>(bufQEs, bufDs, 196, 256, 0);
      attn3_kernel<14><<<dim3(4,12,25),256,0,stream>>>(bufQEs, rhB, rwB, bufDs, bufCs, 196);
    } else {
      vtrans_kernel<<<dim3(64, 12),256,0,stream>>>(bufQEs, bufDs, 4096, 4096, 1);
      attn4_kernel<<<dim3(64,12),256,0,stream>>>(bufQEs, rhB, rwB, bufDs, bufCs);
    }
    gemm_bf16_kernel<64,128><<<dim3(768/128, CDIV(M,64)),256,0,stream>>>(
        bufCs, wpT, proj_b + i*768, nullptr, bufD, nullptr, M, 768, 768, 0);
    if (wsz > 0)
      unpart_add_kernel<<<CDIV(4096*192,256),256,0,stream>>>(xbuf, bufD);
    else
      add4_kernel<<<CDIV(786432,256),256,0,stream>>>((float4*)xbuf, (const float4*)bufD, 786432);
    // MLP
    ln_kernel<<<1024,256,0,stream>>>(xbuf, ln2_g + i*768, ln2_b + i*768, nullptr, bufCs, 768, 1e-5f, 4096);
    gemm_bf16_kernel<128,128><<<dim3(3072/128, 4096/128),256,0,stream>>>(
        bufCs, wf1T, fc1_b + i*3072, nullptr, nullptr, bufQEs, 4096, 3072, 768, 1);
    gemm_bf16_kernel<64,128><<<dim3(768/128, 4096/64),256,0,stream>>>(
        bufQEs, wf2T, fc2_b + i*768, xbuf, xbuf, (i==3) ? bufCs : nullptr, 4096, 768, 3072, 0);
  }

  // neck
  transpose_cvt_kernel<<<dim3(256/32, 768/32),256,0,stream>>>(nconv1, wnT, 768, 256);
  transpose_cvt_kernel<<<dim3(256/32, 2304/32),256,0,stream>>>(nconv2, wn2T, 2304, 256);
  gemm_bf16_kernel<64,64><<<dim3(256/64, 4096/64),256,0,stream>>>(
      bufCs, wnT, nullptr, nullptr, bufD, nullptr, 4096, 256, 768, 0);
  ln_kernel<<<1024,256,0,stream>>>(bufD, nln1_g, nln1_b, nullptr, bufCs, 256, 1e-6f, 4096);
  im2col3_kernel<<<CDIV(4096*288,256),256,0,stream>>>(bufCs, bufQEs);
  gemm_bf16_kernel<64,64><<<dim3(256/64, 4096/64),256,0,stream>>>(
      bufQEs, wn2T, nullptr, nullptr, bufD, nullptr, 4096, 256, 2304, 0);
  ln_kernel<<<1024,256,0,stream>>>(bufD, nln2_g, nln2_b, bufQE, nullptr, 256, 1e-6f, 4096);
  transpose_f32_kernel<<<dim3(256/32, 4096/32),256,0,stream>>>(bufQE, (float*)d_out, 4096, 256);
}

// Round 9
// 1717.428 us; speedup vs baseline: 1.0085x; 1.0021x over previous
//
#include <hip/hip_runtime.h>
#include <math.h>

#define CDIV(a,b) (((a)+(b)-1)/(b))

typedef __attribute__((ext_vector_type(8))) short short8v;   // 8 bf16 = 4 VGPRs
typedef __attribute__((ext_vector_type(4))) float float4v;
typedef __attribute__((ext_vector_type(2))) float float2v;
typedef __attribute__((ext_vector_type(2))) __bf16 bf16x2v;

__device__ __forceinline__ ushort f2b(float f) {
  union { float f; unsigned u; } v; v.f = f;
  unsigned r = (v.u + 0x7fffu + ((v.u >> 16) & 1u)) >> 16;   // RNE
  return (ushort)r;
}
__device__ __forceinline__ float b2f(ushort h) {
  union { unsigned u; float f; } v; v.u = ((unsigned)h) << 16;
  return v.f;
}

// async global->LDS, 16B per lane; lds base must be wave-uniform (HW adds lane*16)
__device__ __forceinline__ void gload_lds16(const ushort* g, ushort* l) {
  __builtin_amdgcn_global_load_lds(
      (const __attribute__((address_space(1))) void*)g,
      (__attribute__((address_space(3))) void*)l, 16, 0, 0);
}

// ---------------------------------------------------------------- elementwise (vectorized)
__global__ __launch_bounds__(256) void copy4_kernel(float4* __restrict__ dst,
                                                    const float4* __restrict__ src, int n4) {
  int i = blockIdx.x*256 + threadIdx.x;
  if (i < n4) dst[i] = src[i];
}

__global__ __launch_bounds__(256) void add4_kernel(float4* __restrict__ x,
                                                   const float4* __restrict__ y, int n4) {
  int i = blockIdx.x*256 + threadIdx.x;
  if (i >= n4) return;
  float4 a = x[i], b = y[i];
  a.x += b.x; a.y += b.y; a.z += b.z; a.w += b.w;
  x[i] = a;
}

// ---------------------------------------------------------------- LayerNorm, one wave per row
__global__ __launch_bounds__(256) void ln_kernel(const float* __restrict__ in,
    const float* __restrict__ g, const float* __restrict__ b,
    float* __restrict__ outf, ushort* __restrict__ outb, int C, float eps, int nrows)
{
  int row = blockIdx.x*4 + (threadIdx.x >> 6);
  int lane = threadIdx.x & 63;
  if (row >= nrows) return;
  const float* rp = in + (size_t)row*C;
  float s = 0.f, s2 = 0.f;
  for (int c = lane; c < C; c += 64) { float v = rp[c]; s += v; s2 += v*v; }
  #pragma unroll
  for (int off = 32; off > 0; off >>= 1) { s += __shfl_xor(s, off); s2 += __shfl_xor(s2, off); }
  float mean = s / C;
  float var  = s2 / C - mean*mean;
  float inv  = rsqrtf(var + eps);
  for (int c = lane; c < C; c += 64) {
    float v = (rp[c]-mean)*inv*g[c] + b[c];
    if (outb) outb[(size_t)row*C + c] = f2b(v);
    else      outf[(size_t)row*C + c] = v;
  }
}

// ---------------------------------------------------------------- window partition (bf16, 8-wide)
__global__ __launch_bounds__(256) void winpart_kernel(const ushort* __restrict__ in,
                                                      ushort* __restrict__ out) {
  int i = blockIdx.x*256 + threadIdx.x;          // over 25*196*96 uint4 units
  if (i >= 25*196*96) return;
  int c8 = i % 96; int t = (i / 96) % 196; int b = i / (96*196);
  int wy = b / 5, wx = b % 5;
  int iy = t / 14, ix = t % 14;
  int h = wy*14 + iy, w = wx*14 + ix;
  uint4 v = {0u,0u,0u,0u};
  if (h < 64 && w < 64) v = *(const uint4*)(in + ((size_t)(h*64 + w))*768 + c8*8);
  *(uint4*)(out + (size_t)i*8) = v;
}

// window unpartition + residual add (float4)
__global__ __launch_bounds__(256) void unpart_add_kernel(float* __restrict__ x,
                                                         const float* __restrict__ p) {
  int i = blockIdx.x*256 + threadIdx.x;          // over 4096*192 float4 units
  if (i >= 4096*192) return;
  int c4 = i % 192; int hw = i / 192; int w = hw % 64; int h = hw / 64;
  int wy = h/14, iy = h%14, wx = w/14, ix = w%14;
  int b = wy*5 + wx; int t = iy*14 + ix;
  float4 a = *(const float4*)(x + (size_t)i*4);
  float4 r = *(const float4*)(p + ((size_t)(b*196 + t))*768 + c4*4);
  a.x += r.x; a.y += r.y; a.z += r.z; a.w += r.w;
  *(float4*)(x + (size_t)i*4) = a;
}

// ---------------------------------------------------------------- weight transpose+convert: in [K][N] f32 -> out [N][K] bf16
__global__ __launch_bounds__(256) void transpose_cvt_kernel(const float* __restrict__ in,
    ushort* __restrict__ out, int K, int N)
{
  __shared__ float t[32][33];
  int n0 = blockIdx.x*32, k0 = blockIdx.y*32;
  int cc = threadIdx.x & 31, rr = threadIdx.x >> 5;
  for (int r = rr; r < 32; r += 8) t[r][cc] = in[(size_t)(k0+r)*N + n0 + cc];
  __syncthreads();
  for (int r = rr; r < 32; r += 8) out[(size_t)(n0+r)*K + k0 + cc] = f2b(t[cc][r]);
}

// f32 transpose: in [R][Cc] -> out [Cc][R]  (for NHWC->NCHW)
__global__ __launch_bounds__(256) void transpose_f32_kernel(const float* __restrict__ in,
    float* __restrict__ out, int R, int Cc)
{
  __shared__ float t[32][33];
  int c0 = blockIdx.x*32, r0 = blockIdx.y*32;
  int cc = threadIdx.x & 31, rr = threadIdx.x >> 5;
  for (int r = rr; r < 32; r += 8) t[r][cc] = in[(size_t)(r0+r)*Cc + c0 + cc];
  __syncthreads();
  for (int r = rr; r < 32; r += 8) out[(size_t)(c0+r)*R + r0 + cc] = t[cc][r];
}

// ---------------------------------------------------------------- V transpose: qkv v-slice -> vt[wn][64 dim][strideV keys] bf16
// perm!=0: within each 64-key tile, physical column p holds key (p&3)*16 + (p>>2)
// (matches attn4's packed-b64 P layout; PV sum is permutation-invariant)
__global__ __launch_bounds__(256) void vtrans_kernel(const ushort* __restrict__ qkv,
    ushort* __restrict__ vt, int T, int strideV, int perm)
{
  __shared__ ushort tile[64*72];
  int kt = blockIdx.x, wn = blockIdx.y;
  int win = wn / 12, n = wn - win*12;
  int tid = threadIdx.x;
  size_t tokBase = (size_t)win * T;
  int k0 = kt*64;
  #pragma unroll
  for (int it=0; it<2; ++it) {
    int id = tid + it*256;
    int r = id >> 3, ch = id & 7;
    int kk = k0 + r; if (kk >= T) kk = T-1;
    *(uint4*)(tile + r*72 + ch*8) =
      *(const uint4*)(qkv + (tokBase + kk)*2304 + 1536 + n*64 + ch*8);
  }
  __syncthreads();
  #pragma unroll
  for (int it=0; it<2; ++it) {
    int id = tid + it*256;
    int d = id & 63, kg = id >> 6;     // kg 0..7
    union { uint4 v; ushort u[8]; } o;
    #pragma unroll
    for (int j=0;j<8;++j) {
      int p = kg*8 + j;
      int kl = perm ? ((p & 3)*16 + (p >> 2)) : p;
      o.u[j] = tile[kl*72 + d];
    }
    *(uint4*)(vt + ((size_t)wn*64 + d)*strideV + k0 + kg*8) = o.v;
  }
}

// ---------------------------------------------------------------- bf16 MFMA GEMM
// m97 structure + bijective XCD swizzle (m204), templated tile:
//   <128,128>: 2x2 waves, 64x64/wave (original)
//   <64,128>:  1x4 waves, 64x32/wave  (narrow-N: proj, fc2 — doubles grid)
//   <64,64>:   1x4 waves, 64x16/wave  (neck convs — 4x grid)
// Staging: (BM+BN)/16 16-row DMA slots round-robin over 4 waves (all configs divide).
template<int BM, int BN>
__global__ __launch_bounds__(256) void gemm_bf16_kernel(
    const ushort* __restrict__ A, const ushort* __restrict__ Bt,
    const float* __restrict__ bias, const float* __restrict__ res,
    float* __restrict__ Cf, ushort* __restrict__ Cb,
    int M, int N, int K, int act)
{
  constexpr int WMW = (BM == 128) ? 2 : 1;   // waves along M
  constexpr int WNW = 4 / WMW;               // waves along N
  constexpr int MI  = BM / (WMW*16);
  constexpr int NI  = BN / (WNW*16);
  constexpr int ASLOTS = BM/16;
  constexpr int TSLOTS = (BM+BN)/16;
  constexpr int NSLOT  = TSLOTS/4;           // per-wave DMA slots

  __shared__ ushort Al[BM*32];
  __shared__ ushort Bl[BN*32];
  int tid = threadIdx.x;
  int lane = tid & 63, wave = tid >> 6;
  int wm = (WMW==2) ? (wave & 1) : 0;
  int wn = (WMW==2) ? (wave >> 1) : wave;
  int l15 = lane & 15, lq = lane >> 4;

  // bijective XCD-aware remap (m204)
  int gx = gridDim.x;
  int nwg = gx * gridDim.y;
  int orig = blockIdx.y * gx + blockIdx.x;
  int q8 = nwg >> 3, r8 = nwg & 7;
  int xcd = orig & 7, within = orig >> 3;
  int lin = (xcd < r8 ? xcd*(q8+1) : r8*(q8+1) + (xcd-r8)*q8) + within;
  int bx = lin % gx, by = lin / gx;

  int rowBase = by * BM, colBase = bx * BN;
  float4v acc[MI][NI];
  #pragma unroll
  for (int i=0;i<MI;++i)
    #pragma unroll
    for (int j=0;j<NI;++j) acc[i][j] = (float4v){0.f,0.f,0.f,0.f};

  int cs  = (lane&3) ^ ((lane>>3)&3);   // staged source chunk (XOR key = (row>>1)&3)
  int rsl = lane >> 2;                  // row within 16-row slot

  const ushort* gsrc[NSLOT];
  ushort* ldst[NSLOT];
  #pragma unroll
  for (int s=0; s<NSLOT; ++s) {
    int ls = wave + 4*s;
    if (ls < ASLOTS) {
      int gr = rowBase + ls*16 + rsl; if (gr >= M) gr = M-1;
      gsrc[s] = A + (size_t)gr*K + cs*8;
      ldst[s] = Al + (ls*16)*32;
    } else {
      int lb = ls - ASLOTS;
      int gc = colBase + lb*16 + rsl;          // N % BN == 0 at all call sites
      gsrc[s] = Bt + (size_t)gc*K + cs*8;
      ldst[s] = Bl + (lb*16)*32;
    }
  }

  int sA = (l15 >> 1) & 3;
  int rdOff = ((lq ^ sA) << 3);

  for (int k0 = 0; k0 < K; k0 += 32) {
    __syncthreads();
    #pragma unroll
    for (int s=0; s<NSLOT; ++s) gload_lds16(gsrc[s] + k0, ldst[s]);
    __syncthreads();
    short8v af[MI], bf[NI];
    #pragma unroll
    for (int mi=0; mi<MI; ++mi)
      af[mi] = *(const short8v*)(Al + (wm*(BM/WMW) + mi*16 + l15)*32 + rdOff);
    #pragma unroll
    for (int ni=0; ni<NI; ++ni)
      bf[ni] = *(const short8v*)(Bl + (wn*(BN/WNW) + ni*16 + l15)*32 + rdOff);
    #pragma unroll
    for (int mi=0; mi<MI; ++mi)
      #pragma unroll
      for (int ni=0; ni<NI; ++ni)
        acc[mi][ni] = __builtin_amdgcn_mfma_f32_16x16x32_bf16(af[mi], bf[ni], acc[mi][ni], 0, 0, 0);
  }
  #pragma unroll
  for (int mi=0; mi<MI; ++mi) {
    int gr0e = rowBase + wm*(BM/WMW) + mi*16 + lq*4;
    #pragma unroll
    for (int ni=0; ni<NI; ++ni) {
      int gc = colBase + wn*(BN/WNW) + ni*16 + l15;
      float bsv = bias ? bias[gc] : 0.f;
      #pragma unroll
      for (int r=0; r<4; ++r) {
        int gr = gr0e + r;
        if (gr < M) {
          float v = acc[mi][ni][r] + bsv;
          if (act) v = 0.5f*v*(1.f + erff(v*0.70710678118f));
          if (res) v += res[(size_t)gr*N + gc];
          if (Cf) Cf[(size_t)gr*N + gc] = v;
          if (Cb) Cb[(size_t)gr*N + gc] = f2b(v);
        }
      }
    }
  }
}

// ---------------------------------------------------------------- im2col for 3x3 SAME conv, bf16, 64x64x256
__global__ __launch_bounds__(256) void im2col3_kernel(const ushort* __restrict__ in,
                                                      ushort* __restrict__ out)
{
  int gid = blockIdx.x*256 + threadIdx.x;      // over 4096*288 uint4 units
  if (gid >= 4096*288) return;
  int u = gid % 288;  int p = gid / 288;
  int x = p & 63, y = p >> 6;
  int tap = u >> 5;
  int cu  = u & 31;
  int dy = tap / 3, dx = tap - dy*3;
  int yy = y + dy - 1, xx = x + dx - 1;
  uint4 v = {0u,0u,0u,0u};
  if (yy >= 0 && yy < 64 && xx >= 0 && xx < 64)
    v = *(const uint4*)(in + ((size_t)(yy*64 + xx))*256 + cu*8);
  *(uint4*)(out + (size_t)p*2304 + u*8) = v;
}

// ---------------------------------------------------------------- decomposed rel-pos bias (bf16 qkv in, bf16 out)
// vectorized loads (short8 q, float4 table); fma chain order preserved exactly.
__global__ __launch_bounds__(256) void relbias_kernel(const ushort* __restrict__ qkv,
    const float* __restrict__ table, ushort* __restrict__ out,
    int nWin, int T, int S, int useH)
{
  int gid = blockIdx.x*256 + threadIdx.x;
  int total = nWin*12*T*S;
  if (gid >= total) return;
  int kk = gid % S; int r = gid / S;
  int t = r % T; int r2 = r / T; int n = r2 % 12; int b = r2 / 12;
  int coord = useH ? (t / S) : (t % S);
  const ushort* q = qkv + ((size_t)(b*T + t))*2304 + n*64;
  const float* tb = table + (size_t)(coord - kk + S - 1)*64;
  float s0=0.f, s1=0.f;
  #pragma unroll
  for (int d8=0; d8<8; ++d8) {
    short8v qv = *(const short8v*)(q + d8*8);
    float4 ta = *(const float4*)(tb + d8*8);
    float4 tc = *(const float4*)(tb + d8*8 + 4);
    s0 = fmaf(b2f((ushort)qv[0]), ta.x, s0);
    s1 = fmaf(b2f((ushort)qv[1]), ta.y, s1);
    s0 = fmaf(b2f((ushort)qv[2]), ta.z, s0);
    s1 = fmaf(b2f((ushort)qv[3]), ta.w, s1);
    s0 = fmaf(b2f((ushort)qv[4]), tc.x, s0);
    s1 = fmaf(b2f((ushort)qv[5]), tc.y, s1);
    s0 = fmaf(b2f((ushort)qv[6]), tc.z, s0);
    s1 = fmaf(b2f((ushort)qv[7]), tc.w, s1);
  }
  out[gid] = f2b(s0 + s1);
}

// ---------------------------------------------------------------- MFMA flash attention (windowed)
// Fixed-max softmax (M0=8 folded into RWl), deferred l-reduce, pre-transposed V.
template<int S>
__global__ __launch_bounds__(256) void attn3_kernel(
    const ushort* __restrict__ qkv, const ushort* __restrict__ rh,
    const ushort* __restrict__ rw, const ushort* __restrict__ vtw,
    ushort* __restrict__ outb, int T)
{
  constexpr int SP = (S + 15) & ~15;
  __shared__ ushort Ql[64*72];
  __shared__ ushort Kl[64*72];
  __shared__ ushort Vt[64*72];
  __shared__ ushort Pl[64*72];
  __shared__ ushort RHl[64*SP];
  __shared__ ushort RWl[64*SP];

  int qt = blockIdx.x, n = blockIdx.y, b = blockIdx.z;
  int wn = b*12 + n;
  int tid = threadIdx.x, lane = tid & 63, w = tid >> 6;
  int l15 = lane & 15, lq = lane >> 4;
  size_t tokBase = (size_t)b * T;
  int q0 = qt * 64;

  #pragma unroll
  for (int it = 0; it < 2; ++it) {
    int id = tid + it*256;
    int r = id >> 3, ch = id & 7;
    int qq = q0 + r; if (qq >= T) qq = T - 1;
    *(uint4*)(Ql + r*72 + ch*8) =
        *(const uint4*)(qkv + (tokBase + qq)*2304 + n*64 + ch*8);
  }
  for (int idx = tid; idx < 64*S; idx += 256) {
    int r = idx / S, c = idx - r*S;
    int qq = q0 + r; if (qq >= T) qq = T - 1;
    size_t base = ((size_t)(b*12 + n)*T + qq)*S;
    RHl[r*SP + c] = rh[base + c];
    RWl[r*SP + c] = f2b(b2f(rw[base + c]) - 8.0f);   // fold fixed max
  }
  __syncthreads();
  short8v aq0 = *(const short8v*)(Ql + (w*16 + l15)*72 + lq*8);
  short8v aq1 = *(const short8v*)(Ql + (w*16 + l15)*72 + 32 + lq*8);

  float lacc[4] = {0.f,0.f,0.f,0.f};
  float4v O[4];
  #pragma unroll
  for (int i=0;i<4;++i) O[i] = (float4v){0.f,0.f,0.f,0.f};

  int nkt = (T + 63) >> 6;
  for (int kt = 0; kt < nkt; ++kt) {
    int k0 = kt*64;
    __syncthreads();
    #pragma unroll
    for (int it=0; it<2; ++it) {
      int id = tid + it*256;
      int r = id >> 3, ch = id & 7;
      int kk = k0 + r; if (kk >= T) kk = T-1;
      *(uint4*)(Kl + r*72 + ch*8) =
        *(const uint4*)(qkv + (tokBase + kk)*2304 + 768 + n*64 + ch*8);
      *(uint4*)(Vt + r*72 + ch*8) =
        *(const uint4*)(vtw + ((size_t)wn*64 + r)*256 + k0 + ch*8);
    }
    __syncthreads();

    float4v Sv[4];
    #pragma unroll
    for (int ni=0; ni<4; ++ni) {
      short8v bk0 = *(const short8v*)(Kl + (ni*16 + l15)*72 + lq*8);
      short8v bk1 = *(const short8v*)(Kl + (ni*16 + l15)*72 + 32 + lq*8);
      float4v s = (float4v){0.f,0.f,0.f,0.f};
      s = __builtin_amdgcn_mfma_f32_16x16x32_bf16(aq0, bk0, s, 0,0,0);
      s = __builtin_amdgcn_mfma_f32_16x16x32_bf16(aq1, bk1, s, 0,0,0);
      Sv[ni] = s;
    }

    #pragma unroll
    for (int r=0;r<4;++r) {
      int qlrow = w*16 + lq*4 + r;
      #pragma unroll
      for (int ni=0;ni<4;++ni) {
        int key = k0 + ni*16 + l15;
        int kcl = key < T ? key : 0;
        int kh = kcl / S, kw = kcl - kh*S;
        float sc = key < T
          ? fmaf(Sv[ni][r], 0.125f, b2f(RHl[qlrow*SP+kh]) + b2f(RWl[qlrow*SP+kw]))
          : -1e30f;
        float pv = __expf(sc);
        lacc[r] += pv;
        union { float f; unsigned u; } cv; cv.f = pv;
        Pl[qlrow*72 + ni*16 + l15] = (ushort)((cv.u + 0x8000u) >> 16);
      }
    }

    short8v ap0 = *(const short8v*)(Pl + (w*16 + l15)*72 + lq*8);
    short8v ap1 = *(const short8v*)(Pl + (w*16 + l15)*72 + 32 + lq*8);
    #pragma unroll
    for (int ni=0;ni<4;++ni) {
      short8v bv0 = *(const short8v*)(Vt + (ni*16 + l15)*72 + lq*8);
      short8v bv1 = *(const short8v*)(Vt + (ni*16 + l15)*72 + 32 + lq*8);
      O[ni] = __builtin_amdgcn_mfma_f32_16x16x32_bf16(ap0, bv0, O[ni], 0,0,0);
      O[ni] = __builtin_amdgcn_mfma_f32_16x16x32_bf16(ap1, bv1, O[ni], 0,0,0);
    }
  }

  #pragma unroll
  for (int r=0;r<4;++r) {
    int qlrow = w*16 + lq*4 + r;
    int qg = q0 + qlrow;
    float ls = lacc[r];
    #pragma unroll
    for (int off=1; off<16; off<<=1) ls += __shfl_xor(ls, off);
    if (qg < T) {
      float inv = 1.f / ls;
      #pragma unroll
      for (int ni=0;ni<4;++ni)
        outb[(tokBase + qg)*768 + n*64 + ni*16 + l15] = f2b(O[ni][r]*inv);
    }
  }
}

// ---------------------------------------------------------------- specialized global flash attention (T=4096, S=64)
// v10 = v6 structure (best: 117.9us) with the P conversion+pack done via
// __builtin_convertvector(float2 -> bf16x2): compiler emits v_cvt_pk_bf16_f32
// (exact RNE == f2b) WITHOUT asm register pinning (the m240-consistent form).
// lacc accumulation order unchanged. Everything else identical to v6.
__global__ __launch_bounds__(256) void attn4_kernel(
    const ushort* __restrict__ qkv, const ushort* __restrict__ rh,
    const ushort* __restrict__ rw, const ushort* __restrict__ vtg,
    ushort* __restrict__ outb)
{
  const int T = 4096;
  __shared__ ushort Kl[2][64*64];     // linear rows (128B); phys chunk c holds logical chunk c^(row&7)
  __shared__ ushort Vl[2][64*64];
  __shared__ ushort Pl[64*64];        // wave-private rows, same chunk swizzle
  __shared__ ushort RHl[64*72];       // stride 72 (144B, 16B-aligned rows)

  int qt = blockIdx.x, n = blockIdx.y;
  int tid = threadIdx.x, lane = tid & 63, w = tid >> 6;
  int l15 = lane & 15, lq = lane >> 4;
  int q0 = qt * 64;

  // RH rows, wave-private mapping: wave w stages exactly rows w*16..w*16+15
  #pragma unroll
  for (int it = 0; it < 2; ++it) {
    int id2 = lane + it*64;
    int r = w*16 + (id2 >> 3), ch = id2 & 7;
    *(uint4*)(RHl + r*72 + ch*8) =
        *(const uint4*)(rh + ((size_t)n*T + q0 + r)*64 + ch*8);
  }
  // Q fragments straight from global (one-shot, no LDS round-trip)
  const ushort* qp = qkv + (size_t)(q0 + w*16 + l15)*2304 + n*64 + lq*8;
  short8v aq0 = *(const short8v*)(qp);
  short8v aq1 = *(const short8v*)(qp + 32);

  // preload this lane's rw values (kw fixed across tiles), fold fixed max -8
  float rwp[4][4];
  #pragma unroll
  for (int r=0;r<4;++r)
    #pragma unroll
    for (int ni=0;ni<4;++ni)
      rwp[r][ni] = b2f(rw[((size_t)n*T + q0 + w*16 + lq*4 + r)*64 + ni*16 + l15]) - 8.0f;

  const ushort* kbase = qkv + 768 + n*64;          // + row*2304
  const ushort* vbase = vtg + (size_t)n*64*4096;   // [dim][keypos] (columns tile-permuted)
  int sr  = (lane >> 3) & 7;                       // staged row-within-8
  int sch = lane & 7;                              // staged (physical) chunk = lane&7
  int swz = ((sch ^ sr) << 3);                     // inverse-swizzled logical source chunk (ushorts)

  // per wave: 4 DMA loads/tile (2 K + 2 V), rows w*16..w*16+15, LDS dest linear
  auto stage = [&](int buf, int k0s) {
    #pragma unroll
    for (int it=0; it<2; ++it) {
      int rr = w*16 + it*8 + sr;
      gload_lds16(kbase + (size_t)(k0s + rr)*2304 + swz, &Kl[buf][(w*2+it)*512]);
      gload_lds16(vbase + (size_t)rr*4096 + k0s + swz, &Vl[buf][(w*2+it)*512]);
    }
  };

  float lacc[4] = {0.f,0.f,0.f,0.f};
  float4v O[4];
  #pragma unroll
  for (int i=0;i<4;++i) O[i] = (float4v){0.f,0.f,0.f,0.f};

  stage(0, 0);

  int xk  = (lq ^ (l15 & 7)) << 3;          // chunk lq   swizzled read offset (ushorts)
  int xk4 = ((lq ^ 4) ^ (l15 & 7)) << 3;    // chunk lq+4 swizzled

  for (int kt = 0; kt < 64; ++kt) {
    int cur = kt & 1;
    __syncthreads();
    if (kt < 63) stage(cur ^ 1, (kt+1)*64);

    const ushort* Kc = Kl[cur];
    const ushort* Vc = Vl[cur];

    float4v Sv[4];
    #pragma unroll
    for (int ni=0; ni<4; ++ni) {
      short8v bk0 = *(const short8v*)(Kc + (ni*16 + l15)*64 + xk);
      short8v bk1 = *(const short8v*)(Kc + (ni*16 + l15)*64 + xk4);
      float4v s = (float4v){0.f,0.f,0.f,0.f};
      s = __builtin_amdgcn_mfma_f32_16x16x32_bf16(aq0, bk0, s, 0,0,0);
      s = __builtin_amdgcn_mfma_f32_16x16x32_bf16(aq1, bk1, s, 0,0,0);
      Sv[ni] = s;
    }

    // softmax (fixed max, deferred l) + packed P write:
    // physical key position p = l15*4 + ni; V columns hold key (p&3)*16+(p>>2) = ni*16+l15
    #pragma unroll
    for (int r=0;r<4;++r) {
      int qlrow = w*16 + lq*4 + r;
      float rhv = b2f(RHl[qlrow*72 + kt]);           // broadcast per lq-group
      float pv0 = __expf(fmaf(Sv[0][r], 0.125f, rhv + rwp[r][0]));
      lacc[r] += pv0;
      float pv1 = __expf(fmaf(Sv[1][r], 0.125f, rhv + rwp[r][1]));
      lacc[r] += pv1;
      float pv2 = __expf(fmaf(Sv[2][r], 0.125f, rhv + rwp[r][2]));
      lacc[r] += pv2;
      float pv3 = __expf(fmaf(Sv[3][r], 0.125f, rhv + rwp[r][3]));
      lacc[r] += pv3;
      float2v f01 = {pv0, pv1}, f23 = {pv2, pv3};
      bf16x2v b01 = __builtin_convertvector(f01, bf16x2v);   // v_cvt_pk_bf16_f32 (RNE)
      bf16x2v b23 = __builtin_convertvector(f23, bf16x2v);
      unsigned ulo = *(unsigned*)&b01, uhi = *(unsigned*)&b23;
      unsigned long long pk = ((unsigned long long)uhi << 32) | (unsigned long long)ulo;
      *(unsigned long long*)(Pl + qlrow*64 +
          ((((l15 >> 1)) ^ (qlrow & 7)) << 3) + (l15 & 1)*4) = pk;
    }

    // P rows are wave-private -> no barrier needed between write and read
    short8v ap0 = *(const short8v*)(Pl + (w*16 + l15)*64 + xk);
    short8v ap1 = *(const short8v*)(Pl + (w*16 + l15)*64 + xk4);
    #pragma unroll
    for (int ni=0;ni<4;++ni) {
      short8v bv0 = *(const short8v*)(Vc + (ni*16 + l15)*64 + xk);
      short8v bv1 = *(const short8v*)(Vc + (ni*16 + l15)*64 + xk4);
      O[ni] = __builtin_amdgcn_mfma_f32_16x16x32_bf16(ap0, bv0, O[ni], 0,0,0);
      O[ni] = __builtin_amdgcn_mfma_f32_16x16x32_bf16(ap1, bv1, O[ni], 0,0,0);
    }
  }

  #pragma unroll
  for (int r=0;r<4;++r) {
    int qg = q0 + w*16 + lq*4 + r;
    float ls = lacc[r];
    #pragma unroll
    for (int off=1; off<16; off<<=1) ls += __shfl_xor(ls, off);
    float inv = 1.f / ls;
    #pragma unroll
    for (int ni=0;ni<4;++ni)
      outb[(size_t)qg*768 + n*64 + ni*16 + l15] = f2b(O[ni][r]*inv);
  }
}

// ================================================================ launch
extern "C" void kernel_launch(void* const* d_in, const int* in_sizes, int n_in,
                              void* d_out, int out_size, void* d_ws, size_t ws_size,
                              hipStream_t stream)
{
  const float* x_in   = (const float*)d_in[0];
  const float* ln1_g  = (const float*)d_in[1];
  const float* ln1_b  = (const float*)d_in[2];
  const float* qkv_w  = (const float*)d_in[3];
  const float* qkv_b  = (const float*)d_in[4];
  const float* proj_w = (const float*)d_in[5];
  const float* proj_b = (const float*)d_in[6];
  const float* rel_h  = (const float*)d_in[7];
  const float* rel_w  = (const float*)d_in[8];
  const float* ln2_g  = (const float*)d_in[9];
  const float* ln2_b  = (const float*)d_in[10];
  const float* fc1_w  = (const float*)d_in[11];
  const float* fc1_b  = (const float*)d_in[12];
  const float* fc2_w  = (const float*)d_in[13];
  const float* fc2_b  = (const float*)d_in[14];
  const float* nconv1 = (const float*)d_in[15];
  const float* nln1_g = (const float*)d_in[16];
  const float* nln1_b = (const float*)d_in[17];
  const float* nconv2 = (const float*)d_in[18];
  const float* nln2_g = (const float*)d_in[19];
  const float* nln2_b = (const float*)d_in[20];

  // workspace layout (floats); total ~108.9 MB
  float*  ws     = (float*)d_ws;
  float*  xbuf   = ws;                                   // 3,145,728 fl
  ushort* bufCs  = (ushort*)(xbuf + 3145728);            // 3,763,200 sh
  float*  bufD   = xbuf + 3145728 + 1881600;             // 3,763,200 fl
  float*  bufQE  = bufD + 3763200;                       // 11,289,600 fl
  ushort* bufQEs = (ushort*)bufQE;
  ushort* rhB    = (ushort*)(bufQE + 11289600);          // 3,145,728 sh
  ushort* rwB    = rhB + 3145728;                        // 3,145,728 sh
  ushort* wqT    = rwB + 3145728;                        // 1,769,472 sh
  ushort* wpT    = wqT + 1769472;                        //   589,824 sh
  ushort* wf1T   = wpT + 589824;                         // 2,359,296 sh
  ushort* wf2T   = wf1T + 2359296;                       // 2,359,296 sh
  ushort* wnT    = wf2T + 2359296;                       //   196,608 sh
  ushort* wn2T   = wnT + 196608;                         //   589,824 sh
  ushort* bufDs  = (ushort*)bufD;                        // also hosts VT during attention

  copy4_kernel<<<CDIV(786432,256),256,0,stream>>>((float4*)xbuf, (const float4*)x_in, 786432);

  for (int i = 0; i < 4; ++i) {
    int wsz = (i < 3) ? 14 : 0;
    transpose_cvt_kernel<<<dim3(2304/32, 768/32),256,0,stream>>>(qkv_w + (size_t)i*768*2304, wqT, 768, 2304);
    transpose_cvt_kernel<<<dim3(768/32,  768/32),256,0,stream>>>(proj_w + (size_t)i*768*768,  wpT, 768, 768);
    transpose_cvt_kernel<<<dim3(3072/32, 768/32),256,0,stream>>>(fc1_w + (size_t)i*768*3072, wf1T, 768, 3072);
    transpose_cvt_kernel<<<dim3(768/32, 3072/32),256,0,stream>>>(fc2_w + (size_t)i*3072*768, wf2T, 3072, 768);

    ln_kernel<<<1024,256,0,stream>>>(xbuf, ln1_g + i*768, ln1_b + i*768, nullptr, bufCs, 768, 1e-5f, 4096);
    int M;
    const ushort* qkvIn;
    int nWin, T, S;
    if (wsz > 0) {
      winpart_kernel<<<CDIV(25*196*96,256),256,0,stream>>>(bufCs, bufDs);
      qkvIn = bufDs; M = 4900; nWin = 25; T = 196; S = 14;
    } else {
      qkvIn = bufCs; M = 4096; nWin = 1; T = 4096; S = 64;
    }
    gemm_bf16_kernel<128,128><<<dim3(2304/128, CDIV(M,128)),256,0,stream>>>(
        qkvIn, wqT, qkv_b + i*2304, nullptr, nullptr, bufQEs, M, 2304, 768, 0);
    int relTot = nWin*12*T*S;
    relbias_kernel<<<CDIV(relTot,256),256,0,stream>>>(bufQEs, rel_h + i*127*64, rhB, nWin, T, S, 1);
    relbias_kernel<<<CDIV(relTot,256),256,0,stream>>>(bufQEs, rel_w + i*127*64, rwB, nWin, T, S, 0);
    if (wsz > 0) {
      vtrans_kernel<<<dim3(4, 300),256,0,stream>>>(bufQEs, bufDs, 196, 256, 0);
      attn3_kernel<14><<<dim3(4,12,25),256,0,stream>>>(bufQEs, rhB, rwB, bufDs, bufCs, 196);
    } else {
      vtrans_kernel<<<dim3(64, 12),256,0,stream>>>(bufQEs, bufDs, 4096, 4096, 1);
      attn4_kernel<<<dim3(64,12),256,0,stream>>>(bufQEs, rhB, rwB, bufDs, bufCs);
    }
    if (wsz > 0) {
      gemm_bf16_kernel<64,128><<<dim3(768/128, CDIV(M,64)),256,0,stream>>>(
          bufCs, wpT, proj_b + i*768, nullptr, bufD, nullptr, M, 768, 768, 0);
      unpart_add_kernel<<<CDIV(4096*192,256),256,0,stream>>>(xbuf, bufD);
    } else {
      // fuse residual add into proj epilogue (res reads xbuf, Cf writes xbuf)
      gemm_bf16_kernel<64,128><<<dim3(768/128, CDIV(M,64)),256,0,stream>>>(
          bufCs, wpT, proj_b + i*768, xbuf, xbuf, nullptr, M, 768, 768, 0);
    }
    // MLP
    ln_kernel<<<1024,256,0,stream>>>(xbuf, ln2_g + i*768, ln2_b + i*768, nullptr, bufCs, 768, 1e-5f, 4096);
    gemm_bf16_kernel<128,128><<<dim3(3072/128, 4096/128),256,0,stream>>>(
        bufCs, wf1T, fc1_b + i*3072, nullptr, nullptr, bufQEs, 4096, 3072, 768, 1);
    gemm_bf16_kernel<64,128><<<dim3(768/128, 4096/64),256,0,stream>>>(
        bufQEs, wf2T, fc2_b + i*768, xbuf, xbuf, (i==3) ? bufCs : nullptr, 4096, 768, 3072, 0);
  }

  // neck
  transpose_cvt_kernel<<<dim3(256/32, 768/32),256,0,stream>>>(nconv1, wnT, 768, 256);
  transpose_cvt_kernel<<<dim3(256/32, 2304/32),256,0,stream>>>(nconv2, wn2T, 2304, 256);
  gemm_bf16_kernel<64,64><<<dim3(256/64, 4096/64),256,0,stream>>>(
      bufCs, wnT, nullptr, nullptr, bufD, nullptr, 4096, 256, 768, 0);
  ln_kernel<<<1024,256,0,stream>>>(bufD, nln1_g, nln1_b, nullptr, bufCs, 256, 1e-6f, 4096);
  im2col3_kernel<<<CDIV(4096*288,256),256,0,stream>>>(bufCs, bufQEs);
  gemm_bf16_kernel<64,64><<<dim3(256/64, 4096/64),256,0,stream>>>(
      bufQEs, wn2T, nullptr, nullptr, bufD, nullptr, 4096, 256, 2304, 0);
  ln_kernel<<<1024,256,0,stream>>>(bufD, nln2_g, nln2_b, bufQE, nullptr, 256, 1e-6f, 4096);
  transpose_f32_kernel<<<dim3(256/32, 4096/32),256,0,stream>>>(bufQE, (float*)d_out, 4096, 256);
}